// Round 7
// baseline (289.256 us; speedup 1.0000x reference)
//
#include <hip/hip_runtime.h>
#include <math.h>

typedef __bf16 bf16;
typedef __bf16 bf16x8 __attribute__((ext_vector_type(8)));
typedef __bf16 bf16x4 __attribute__((ext_vector_type(4)));
typedef float f32x4 __attribute__((ext_vector_type(4)));

// ---------------------------------------------------------------------------
// async global->LDS 16B (direct-to-shared DMA). LDS dest must be
// wave-uniform base + lane*16 — all staging maps below guarantee that.
// ---------------------------------------------------------------------------
__device__ __forceinline__ void ldg_lds16(const bf16* g, bf16* l) {
#if __has_builtin(__builtin_amdgcn_global_load_lds)
    __builtin_amdgcn_global_load_lds(
        (const __attribute__((address_space(1))) void*)g,
        (__attribute__((address_space(3))) void*)l, 16, 0, 0);
#else
    *(bf16x8*)l = *(const bf16x8*)g;
#endif
}

// ---------------------------------------------------------------------------
// cvt_x: fp32 -> bf16, 8 elems/thread, coalesced.
// ---------------------------------------------------------------------------
__global__ void cvt_x(const float* __restrict__ X, bf16* __restrict__ Xb, int total8)
{
    int idx = blockIdx.x * 256 + threadIdx.x;
    if (idx >= total8) return;
    const float* p = X + (size_t)idx * 8;
    f32x4 a = *reinterpret_cast<const f32x4*>(p);
    f32x4 b = *reinterpret_cast<const f32x4*>(p + 4);
    bf16x8 r;
    r[0] = (bf16)a[0]; r[1] = (bf16)a[1]; r[2] = (bf16)a[2]; r[3] = (bf16)a[3];
    r[4] = (bf16)b[0]; r[5] = (bf16)b[1]; r[6] = (bf16)b[2]; r[7] = (bf16)b[3];
    *reinterpret_cast<bf16x8*>(Xb + (size_t)idx * 8) = r;
}

// ---------------------------------------------------------------------------
// cvt_wt3: fused transpose-convert of Wq|Wk|Wv -> Wqkv^T [3072][2048] bf16.
// ---------------------------------------------------------------------------
__global__ void cvt_wt3(const float* __restrict__ Wq, const float* __restrict__ Wk,
                        const float* __restrict__ Wv, bf16* __restrict__ Wt)
{
    __shared__ float t[32][33];
    int bx = blockIdx.x;
    const float* W; int Ncols, nbase;
    if (bx < 64)      { W = Wq; Ncols = 2048; nbase = 0;    }
    else if (bx < 80) { W = Wk; Ncols = 512;  nbase = 2048; bx -= 64; }
    else              { W = Wv; Ncols = 512;  nbase = 2560; bx -= 80; }
    const int n0 = bx * 32, k0 = blockIdx.y * 32;
    const int x = threadIdx.x, y = threadIdx.y;
    #pragma unroll
    for (int i = 0; i < 4; ++i)
        t[y + 8 * i][x] = W[(size_t)(k0 + y + 8 * i) * Ncols + n0 + x];
    __syncthreads();
    #pragma unroll
    for (int i = 0; i < 4; ++i)
        Wt[(size_t)(nbase + n0 + y + 8 * i) * 2048 + k0 + x] = (bf16)t[x][y + 8 * i];
}

// cvt_wt: single-matrix variant (Wo, after QKV GEMM frees its region)
__global__ void cvt_wt(const float* __restrict__ W, bf16* __restrict__ Wt, int Ncols)
{
    __shared__ float t[32][33];
    const int n0 = blockIdx.x * 32, k0 = blockIdx.y * 32;
    const int x = threadIdx.x, y = threadIdx.y;
    #pragma unroll
    for (int i = 0; i < 4; ++i)
        t[y + 8 * i][x] = W[(size_t)(k0 + y + 8 * i) * Ncols + n0 + x];
    __syncthreads();
    #pragma unroll
    for (int i = 0; i < 4; ++i)
        Wt[(size_t)(n0 + y + 8 * i) * 2048 + k0 + x] = (bf16)t[x][y + 8 * i];
}

// ---------------------------------------------------------------------------
// gemm256_qkv: 256Mx192N tile, BK=64, 8 waves (2Mx4N, 128x48 each).
// ROUND-7 CHANGE: BN 256 -> 192 so grid = (3072/192=16, 4096/256=16) = 256
// blocks = 1/CU. The old 256x256 grid was 192 blocks = 75% CU fill, which
// fully explains its 757 TF vs gemm_out's 1011 TF (same schedule, full grid).
// LDS (256+192)x64x2B x 2buf = 112 KB. 7 loads/thread/tile -> vmcnt(7).
// Same proven counted-vmcnt + T2 source-swizzle + setprio skeleton.
// Q/K/V epilogue boundaries (2048, 2560) are 16-aligned -> per-fragment
// region branch stays wave-uniform.
// ---------------------------------------------------------------------------
__global__ __launch_bounds__(512, 2) void gemm256_qkv(
    const bf16* __restrict__ A, const bf16* __restrict__ Bt,
    bf16* __restrict__ Qo, bf16* __restrict__ Ko, bf16* __restrict__ Vt,
    int K)
{
    __shared__ __align__(16) bf16 smem[2 * 28672];   // 112 KB: [buf][A|B]

    const int tid  = threadIdx.x;
    const int lane = tid & 63;
    const int wave = tid >> 6;
    const int quad = lane >> 4;
    const int l16  = lane & 15;
    const int wm   = wave >> 2;          // 0..1  (M half, 128 rows)
    const int wn   = wave & 3;           // 0..3  (48 cols each)

    const int m0 = blockIdx.y * 256;
    const int n0 = blockIdx.x * 192;

    // staging source offsets, global column chunk pre-swizzled (rule #21)
    int offA[4], offB[3];
    #pragma unroll
    for (int p = 0; p < 4; ++p) {
        int u = p * 512 + tid;
        int row = u >> 3;
        int kc8 = (u & 7) ^ (row & 7);
        offA[p] = (m0 + row) * K + kc8 * 8;
    }
    #pragma unroll
    for (int p = 0; p < 3; ++p) {
        int u = p * 512 + tid;
        int row = u >> 3;                // 0..191
        int kc8 = (u & 7) ^ (row & 7);
        offB[p] = (n0 + row) * K + kc8 * 8;
    }
    const int dstoff = tid * 8;

    const int xv = (l16 & 7) << 4;
    const int c0 = ((quad * 16) ^ xv) >> 1;        // chunk quad, read-swizzled
    const int c1 = ((64 + quad * 16) ^ xv) >> 1;   // chunk 4+quad
    const int rA = (wm * 128 + l16) * 64;
    const int rB = (wn * 48 + l16) * 64;

    f32x4 acc[8][3] = {};
    const int NT = K >> 6;               // 32

    auto stage = [&](int tt, int bsel) {
        bf16* as = smem + bsel * 28672;
        bf16* bs = as + 16384;
        const int koff = tt * 64;
        #pragma unroll
        for (int p = 0; p < 4; ++p)
            ldg_lds16(A + offA[p] + koff, as + p * 4096 + dstoff);
        #pragma unroll
        for (int p = 0; p < 3; ++p)
            ldg_lds16(Bt + offB[p] + koff, bs + p * 4096 + dstoff);
    };

    stage(0, 0);
    stage(1, 1);
    asm volatile("s_waitcnt vmcnt(7)" ::: "memory");
    __builtin_amdgcn_sched_barrier(0);
    __builtin_amdgcn_s_barrier();
    __builtin_amdgcn_sched_barrier(0);

    for (int t = 0; t < NT; ++t) {
        const bf16* As = smem + (t & 1) * 28672;
        const bf16* Bs = As + 16384;

        bf16x8 a0[8], b0[3];
        #pragma unroll
        for (int i = 0; i < 8; ++i)
            a0[i] = *(const bf16x8*)(As + rA + i * 1024 + c0);
        #pragma unroll
        for (int i = 0; i < 3; ++i)
            b0[i] = *(const bf16x8*)(Bs + rB + i * 1024 + c0);

        #pragma unroll
        for (int mi = 0; mi < 8; ++mi)
            #pragma unroll
            for (int ni = 0; ni < 3; ++ni)
                acc[mi][ni] = __builtin_amdgcn_mfma_f32_16x16x32_bf16(
                    a0[mi], b0[ni], acc[mi][ni], 0, 0, 0);

        bf16x8 a1[8], b1[3];
        #pragma unroll
        for (int i = 0; i < 8; ++i)
            a1[i] = *(const bf16x8*)(As + rA + i * 1024 + c1);
        #pragma unroll
        for (int i = 0; i < 3; ++i)
            b1[i] = *(const bf16x8*)(Bs + rB + i * 1024 + c1);

        asm volatile("s_waitcnt lgkmcnt(0)" ::: "memory");
        __builtin_amdgcn_sched_barrier(0);
        __builtin_amdgcn_s_barrier();
        __builtin_amdgcn_sched_barrier(0);

        if (t + 2 < NT) stage(t + 2, t & 1);

        __builtin_amdgcn_s_setprio(1);
        #pragma unroll
        for (int mi = 0; mi < 8; ++mi)
            #pragma unroll
            for (int ni = 0; ni < 3; ++ni)
                acc[mi][ni] = __builtin_amdgcn_mfma_f32_16x16x32_bf16(
                    a1[mi], b1[ni], acc[mi][ni], 0, 0, 0);
        __builtin_amdgcn_s_setprio(0);

        if (t + 2 < NT) {
            asm volatile("s_waitcnt vmcnt(7)" ::: "memory");  // tile t+1 landed
            __builtin_amdgcn_sched_barrier(0);
            __builtin_amdgcn_s_barrier();
            __builtin_amdgcn_sched_barrier(0);
        } else if (t == NT - 2) {
            asm volatile("s_waitcnt vmcnt(0)" ::: "memory");
            __builtin_amdgcn_sched_barrier(0);
            __builtin_amdgcn_s_barrier();
            __builtin_amdgcn_sched_barrier(0);
        }
    }

    #pragma unroll
    for (int mi = 0; mi < 8; ++mi) {
        #pragma unroll
        for (int ni = 0; ni < 3; ++ni) {
            const int row = m0 + wm * 128 + mi * 16 + quad * 4;
            const int col = n0 + wn * 48 + ni * 16 + l16;
            const int cb  = n0 + wn * 48 + ni * 16;    // wave-uniform base
            if (cb < 2048) {            // Q region
                #pragma unroll
                for (int r = 0; r < 4; ++r)
                    Qo[(size_t)(row + r) * 2048 + col] = (bf16)acc[mi][ni][r];
            } else if (cb < 2560) {     // K region
                #pragma unroll
                for (int r = 0; r < 4; ++r)
                    Ko[(size_t)(row + r) * 512 + (col - 2048)] = (bf16)acc[mi][ni][r];
            } else {                    // V region -> transposed Vt[d][t]
                bf16x4 v;
                #pragma unroll
                for (int r = 0; r < 4; ++r) v[r] = (bf16)acc[mi][ni][r];
                *reinterpret_cast<bf16x4*>(&Vt[(size_t)(col - 2560) * 4096 + row]) = v;
            }
        }
    }
}

// ---------------------------------------------------------------------------
// gemm_out: C[4096,2048] = A @ Bt^T, fp32 C. 256Mx128N, BK=64, 8 waves,
// counted-vmcnt pipeline. (proven round 4, unchanged)
// ---------------------------------------------------------------------------
__global__ __launch_bounds__(512, 2) void gemm_out(
    const bf16* __restrict__ A, const bf16* __restrict__ Bt,
    float* __restrict__ C, int K)
{
    __shared__ __align__(16) bf16 smem[2 * 24576];   // 96 KB: [buf][A|B]

    const int tid  = threadIdx.x;
    const int lane = tid & 63;
    const int wave = tid >> 6;
    const int quad = lane >> 4;
    const int l16  = lane & 15;
    const int wm   = wave >> 1;
    const int wn   = wave & 1;

    const int m0 = blockIdx.y * 256;
    const int n0 = blockIdx.x * 128;

    int offA[4], offB[2];
    #pragma unroll
    for (int p = 0; p < 4; ++p) {
        int u = p * 512 + tid;
        int row = u >> 3;
        int kc8 = (u & 7) ^ (row & 7);
        offA[p] = (m0 + row) * K + kc8 * 8;
    }
    #pragma unroll
    for (int p = 0; p < 2; ++p) {
        int u = p * 512 + tid;
        int row = u >> 3;
        int kc8 = (u & 7) ^ (row & 7);
        offB[p] = (n0 + row) * K + kc8 * 8;
    }
    const int dstoff = tid * 8;

    const int xv = (l16 & 7) << 4;
    const int c0 = ((quad * 16) ^ xv) >> 1;
    const int c1 = ((64 + quad * 16) ^ xv) >> 1;
    const int rA = (wm * 64 + l16) * 64;
    const int rB = (wn * 64 + l16) * 64;

    f32x4 acc[4][4] = {};
    const int NT = K >> 6;

    auto stage = [&](int tt, int bsel) {
        bf16* as = smem + bsel * 24576;
        bf16* bs = as + 16384;
        const int koff = tt * 64;
        #pragma unroll
        for (int p = 0; p < 4; ++p)
            ldg_lds16(A + offA[p] + koff, as + p * 4096 + dstoff);
        #pragma unroll
        for (int p = 0; p < 2; ++p)
            ldg_lds16(Bt + offB[p] + koff, bs + p * 4096 + dstoff);
    };

    stage(0, 0);
    stage(1, 1);
    asm volatile("s_waitcnt vmcnt(6)" ::: "memory");
    __builtin_amdgcn_sched_barrier(0);
    __builtin_amdgcn_s_barrier();
    __builtin_amdgcn_sched_barrier(0);

    for (int t = 0; t < NT; ++t) {
        const bf16* As = smem + (t & 1) * 24576;
        const bf16* Bs = As + 16384;

        bf16x8 a0[4], b0[4];
        #pragma unroll
        for (int i = 0; i < 4; ++i)
            a0[i] = *(const bf16x8*)(As + rA + i * 1024 + c0);
        #pragma unroll
        for (int i = 0; i < 4; ++i)
            b0[i] = *(const bf16x8*)(Bs + rB + i * 1024 + c0);

        #pragma unroll
        for (int mi = 0; mi < 4; ++mi)
            #pragma unroll
            for (int ni = 0; ni < 4; ++ni)
                acc[mi][ni] = __builtin_amdgcn_mfma_f32_16x16x32_bf16(
                    a0[mi], b0[ni], acc[mi][ni], 0, 0, 0);

        bf16x8 a1[4], b1[4];
        #pragma unroll
        for (int i = 0; i < 4; ++i)
            a1[i] = *(const bf16x8*)(As + rA + i * 1024 + c1);
        #pragma unroll
        for (int i = 0; i < 4; ++i)
            b1[i] = *(const bf16x8*)(Bs + rB + i * 1024 + c1);

        asm volatile("s_waitcnt lgkmcnt(0)" ::: "memory");
        __builtin_amdgcn_sched_barrier(0);
        __builtin_amdgcn_s_barrier();
        __builtin_amdgcn_sched_barrier(0);

        if (t + 2 < NT) stage(t + 2, t & 1);

        __builtin_amdgcn_s_setprio(1);
        #pragma unroll
        for (int mi = 0; mi < 4; ++mi)
            #pragma unroll
            for (int ni = 0; ni < 4; ++ni)
                acc[mi][ni] = __builtin_amdgcn_mfma_f32_16x16x32_bf16(
                    a1[mi], b1[ni], acc[mi][ni], 0, 0, 0);
        __builtin_amdgcn_s_setprio(0);

        if (t + 2 < NT) {
            asm volatile("s_waitcnt vmcnt(6)" ::: "memory");
            __builtin_amdgcn_sched_barrier(0);
            __builtin_amdgcn_s_barrier();
            __builtin_amdgcn_sched_barrier(0);
        } else if (t == NT - 2) {
            asm volatile("s_waitcnt vmcnt(0)" ::: "memory");
            __builtin_amdgcn_sched_barrier(0);
            __builtin_amdgcn_s_barrier();
            __builtin_amdgcn_sched_barrier(0);
        }
    }

    #pragma unroll
    for (int mi = 0; mi < 4; ++mi) {
        #pragma unroll
        for (int ni = 0; ni < 4; ++ni) {
            const int row = m0 + wm * 64 + mi * 16 + quad * 4;
            const int col = n0 + wn * 64 + ni * 16 + l16;
            #pragma unroll
            for (int r = 0; r < 4; ++r)
                C[(size_t)(row + r) * 2048 + col] = acc[mi][ni][r];
        }
    }
}

// ---------------------------------------------------------------------------
// rope_k: RoPE for K [T,4,128] only (Q-RoPE is fused into attn_v10).
// ---------------------------------------------------------------------------
__global__ void rope_k(bf16* __restrict__ Kb, int total)
{
    int idx = blockIdx.x * 256 + threadIdx.x;
    if (idx >= total) return;
    int j  = idx & 63;
    int th = idx >> 6;
    int t  = th >> 2;

    bf16* p = Kb + (size_t)th * 128;
    const float NEG_LN1E4_64 = -0.14391155806323211f;  // -ln(10000)/64
    float inv_freq = expf(NEG_LN1E4_64 * (float)j);
    float ang = (float)t * inv_freq;
    float c = cosf(ang), s = sinf(ang);
    float q0 = (float)p[j], q1 = (float)p[j + 64];
    p[j]      = (bf16)(q0 * c - q1 * s);
    p[j + 64] = (bf16)(q1 * c + q0 * s);
}

// ---------------------------------------------------------------------------
// attn_v10: flash attention, sliding window 1024, causal, GQA.
// EXACT round-4 attn_v7 structure (measured 74.8us) + fused Q-RoPE only.
// Round-6 lesson: v9's packed-XOR Pl + fast-path branch cost ~10us while the
// 487K conflicts they removed are <1us of real time — reverted to stride-72
// Pl and the plain masked path. Q loads issue first so RoPE's data wait
// (in-order vmcnt) leaves the 16 staging loads in flight.
// ---------------------------------------------------------------------------
__global__ __launch_bounds__(256) void attn_v10(
    const bf16* __restrict__ Q, const bf16* __restrict__ K,
    const bf16* __restrict__ Vt, bf16* __restrict__ Y)
{
    const float scale = 0.08838834764831845f;  // 1/sqrt(128)

    __shared__ __align__(16) bf16 Ks[2 * 64 * 128];  // [buf][kk][128d], chunk^=(kk&15)
    __shared__ __align__(16) bf16 Vs[2 * 128 * 64];  // [buf][d][64k],   chunk^=(d&7)
    __shared__ __align__(16) bf16 Pl[4][16 * 72];    // per-wave P[row][64key]

    const int tid  = threadIdx.x;
    const int lane = tid & 63;
    const int wave = tid >> 6;
    const int quad = lane >> 4;
    const int l16  = lane & 15;

    const int i0  = (gridDim.x - 1 - blockIdx.x) * 64;   // long blocks first
    const int h   = blockIdx.y;
    const int kvh = h >> 2;
    const int q0  = i0 + wave * 16;
    bf16* Plw = Pl[wave];

    const int ks = (i0 >= 1024) ? (i0 - 1024) : 0;
    const int nsteps = (i0 + 64 - ks) >> 6;

    auto stage = [&](int tt, int bsel) {
        const int k0s = ks + tt * 64;
        bf16* kd = Ks + bsel * 8192;
        bf16* vd = Vs + bsel * 8192;
        #pragma unroll
        for (int p = 0; p < 4; ++p) {
            int u = p * 256 + tid;
            int kk = u >> 4, sc = u & 15;
            ldg_lds16(K + (size_t)(k0s + kk) * 512 + kvh * 128 + (sc ^ (kk & 15)) * 8,
                      kd + u * 8);
        }
        #pragma unroll
        for (int p = 0; p < 4; ++p) {
            int u = p * 256 + tid;
            int d = u >> 3, sc = u & 7;
            ldg_lds16(Vt + (size_t)(kvh * 128 + d) * 4096 + k0s + (sc ^ (d & 7)) * 8,
                      vd + u * 8);
        }
    };

    // Q raw loads first (oldest vmem ops), then staging issues; the RoPE
    // compute's wait on Q data leaves the staging loads in flight.
    bf16x8 qr_[4];
    {
        const bf16* qp = Q + (size_t)(q0 + l16) * 2048 + h * 128 + quad * 8;
        #pragma unroll
        for (int c = 0; c < 4; ++c)
            qr_[c] = *reinterpret_cast<const bf16x8*>(qp + c * 32);
    }

    // prologue: stage tiles 0 and 1 (tile-1 rows always < 4096 -> in-bounds
    // even when nsteps==1; data simply unused then).
    stage(0, 0);
    stage(1, 1);

    // fused Q-RoPE into A-operand fragments
    bf16x8 qf[4];
    {
        const float NEG_LN1E4_64 = -0.14391155806323211f;  // -ln(10000)/64
        const float tf = (float)(q0 + l16);
        #pragma unroll
        for (int c = 0; c < 2; ++c) {
            #pragma unroll
            for (int i = 0; i < 8; ++i) {
                float inv_freq = expf(NEG_LN1E4_64 * (float)(c * 32 + quad * 8 + i));
                float ang = tf * inv_freq;
                float cs = cosf(ang), sn = sinf(ang);
                float a = (float)qr_[c][i], b = (float)qr_[c + 2][i];
                qf[c][i]     = (bf16)(a * cs - b * sn);
                qf[c + 2][i] = (bf16)(b * cs + a * sn);
            }
        }
    }

    f32x4 o[8] = {};
    float lsum[4] = {0.f, 0.f, 0.f, 0.f};

    asm volatile("s_waitcnt vmcnt(8)" ::: "memory");   // tile 0 landed
    __builtin_amdgcn_sched_barrier(0);
    __builtin_amdgcn_s_barrier();
    __builtin_amdgcn_sched_barrier(0);

    for (int t = 0; t < nsteps; ++t) {
        const int b  = t & 1;
        const int k0 = ks + t * 64;
        const bf16* Kb = Ks + b * 8192;
        const bf16* Vb = Vs + b * 8192;

        // S = Q K^T, four 16-key tiles (B-frags from swizzled Ks)
        f32x4 s[4];
        __builtin_amdgcn_s_setprio(1);
        #pragma unroll
        for (int kh = 0; kh < 4; ++kh) {
            const int kk = kh * 16 + l16;
            f32x4 sv = {};
            #pragma unroll
            for (int c = 0; c < 4; ++c) {
                bf16x8 kf = *reinterpret_cast<const bf16x8*>(
                    &Kb[kk * 128 + (((c * 4 + quad) ^ (kk & 15)) * 8)]);
                sv = __builtin_amdgcn_mfma_f32_16x16x32_bf16(qf[c], kf, sv, 0, 0, 0);
            }
            s[kh] = sv;
        }
        __builtin_amdgcn_s_setprio(0);

        // P = exp(mask(S*scale)) with fixed max 0; per-lane l accumulation
        #pragma unroll
        for (int kh = 0; kh < 4; ++kh) {
            const int key = k0 + kh * 16 + l16;
            #pragma unroll
            for (int r = 0; r < 4; ++r) {
                const int qrow = q0 + quad * 4 + r;
                bool ok = (unsigned)(qrow - key) < 1024u;   // causal & window
                float pv = ok ? __expf(s[kh][r] * scale) : 0.f;
                lsum[r] += pv;
                Plw[(quad * 4 + r) * 72 + kh * 16 + l16] = (bf16)pv;
            }
        }

        // PV: P (A-frags, wave-private LDS) x V (B-frags from swizzled Vs)
        bf16x8 pf0 = *reinterpret_cast<const bf16x8*>(&Plw[l16 * 72 + quad * 8]);
        bf16x8 pf1 = *reinterpret_cast<const bf16x8*>(&Plw[l16 * 72 + 32 + quad * 8]);
        __builtin_amdgcn_s_setprio(1);
        #pragma unroll
        for (int n = 0; n < 8; ++n) {
            const int d = n * 16 + l16;
            bf16x8 v0 = *reinterpret_cast<const bf16x8*>(
                &Vb[d * 64 + (((quad) ^ (d & 7)) * 8)]);
            bf16x8 v1 = *reinterpret_cast<const bf16x8*>(
                &Vb[d * 64 + (((4 + quad) ^ (d & 7)) * 8)]);
            o[n] = __builtin_amdgcn_mfma_f32_16x16x32_bf16(pf0, v0, o[n], 0, 0, 0);
            o[n] = __builtin_amdgcn_mfma_f32_16x16x32_bf16(pf1, v1, o[n], 0, 0, 0);
        }
        __builtin_amdgcn_s_setprio(0);

        // ---- pipeline boundary: all reads of buf b done -> restage it
        asm volatile("s_waitcnt lgkmcnt(0)" ::: "memory");
        __builtin_amdgcn_sched_barrier(0);
        __builtin_amdgcn_s_barrier();
        __builtin_amdgcn_sched_barrier(0);

        if (t + 2 < nsteps) {
            stage(t + 2, b);
            asm volatile("s_waitcnt vmcnt(8)" ::: "memory");  // tile t+1 landed
        } else {
            asm volatile("s_waitcnt vmcnt(0)" ::: "memory");  // drain tail
        }
        __builtin_amdgcn_sched_barrier(0);
        __builtin_amdgcn_s_barrier();
        __builtin_amdgcn_sched_barrier(0);
    }

    // final: reduce l over the 16 lanes of each row (once), normalize, store
    #pragma unroll
    for (int r = 0; r < 4; ++r) {
        #pragma unroll
        for (int off = 1; off < 16; off <<= 1)
            lsum[r] += __shfl_xor(lsum[r], off, 64);
    }
    #pragma unroll
    for (int r = 0; r < 4; ++r) {
        int row = q0 + quad * 4 + r;
        float inv = (lsum[r] > 0.f) ? 1.f / lsum[r] : 0.f;
        #pragma unroll
        for (int n = 0; n < 8; ++n)
            Y[(size_t)row * 2048 + h * 128 + n * 16 + l16] = (bf16)(o[n][r] * inv);
    }
}

// ---------------------------------------------------------------------------
extern "C" void kernel_launch(void* const* d_in, const int* in_sizes, int n_in,
                              void* d_out, int out_size, void* d_ws, size_t ws_size,
                              hipStream_t stream)
{
    const float* x  = (const float*)d_in[0];
    const float* Wq = (const float*)d_in[1];
    const float* Wk = (const float*)d_in[2];
    const float* Wv = (const float*)d_in[3];
    const float* Wo = (const float*)d_in[4];
    float* out = (float*)d_out;

    const int T = 4096, DIM = 2048;

    // d_out (32MB fp32) hosts bf16 intermediates, all dead before final GEMM:
    //   [0,16M) Qb [T,2048] | [16M,20M) Kb [T,512] | [20M,24M) Vt [512][T]
    char* po = (char*)d_out;
    bf16* Qb = (bf16*)(po);
    bf16* Kb = (bf16*)(po + (16u << 20));
    bf16* Vtb = (bf16*)(po + (20u << 20));

    // ws (peak 28MB): [0,16M) xb -> later Yb ; [16M,28M) Wqkv^T -> later Wo^T
    char* ws = (char*)d_ws;
    bf16* xb    = (bf16*)(ws);
    bf16* Wqkvt = (bf16*)(ws + (16u << 20));
    bf16* Yb    = (bf16*)(ws);                 // reuses xb (dead after QKV GEMM)
    bf16* Wot   = (bf16*)(ws + (16u << 20));   // reuses Wqkv^T (dead after QKV GEMM)

    // 1. convert x -> bf16
    cvt_x<<<dim3(T * DIM / 8 / 256), 256, 0, stream>>>(x, xb, T * DIM / 8);

    // 2. fused transpose-convert Wq|Wk|Wv -> Wqkv^T [3072][2048]
    dim3 tb(32, 8);
    cvt_wt3<<<dim3(96, 64), tb, 0, stream>>>(Wq, Wk, Wv, Wqkvt);

    // 3. fused QKV GEMM (256x192 tiles -> 256 blocks, full CU fill)
    gemm256_qkv<<<dim3(3072 / 192, T / 256), 512, 0, stream>>>(
        xb, Wqkvt, Qb, Kb, Vtb, DIM);

    // 4. Wo^T (after QKV GEMM frees the region)
    cvt_wt<<<dim3(2048 / 32, 64), tb, 0, stream>>>(Wo, Wot, 2048);

    // 5. RoPE on K only (Q-RoPE fused into attn_v10)
    int ktot = T * 4 * 64;
    rope_k<<<(ktot + 255) / 256, 256, 0, stream>>>(Kb, ktot);

    // 6. attention (v10 = proven v7 pipeline + fused Q-RoPE)
    attn_v10<<<dim3(T / 64, 16), 256, 0, stream>>>(Qb, Kb, Vtb, Yb);

    // 7. output projection (256x128 deep-pipelined): -> out (fp32)
    gemm_out<<<dim3(2048 / 128, T / 256), 512, 0, stream>>>(
        Yb, Wot, out, DIM);
}

// Round 8
// 278.692 us; speedup vs baseline: 1.0379x; 1.0379x over previous
//
#include <hip/hip_runtime.h>
#include <math.h>

typedef __bf16 bf16;
typedef __bf16 bf16x8 __attribute__((ext_vector_type(8)));
typedef __bf16 bf16x4 __attribute__((ext_vector_type(4)));
typedef float f32x4 __attribute__((ext_vector_type(4)));

// ---------------------------------------------------------------------------
// async global->LDS 16B (direct-to-shared DMA). LDS dest must be
// wave-uniform base + lane*16 — all staging maps below guarantee that.
// ---------------------------------------------------------------------------
__device__ __forceinline__ void ldg_lds16(const bf16* g, bf16* l) {
#if __has_builtin(__builtin_amdgcn_global_load_lds)
    __builtin_amdgcn_global_load_lds(
        (const __attribute__((address_space(1))) void*)g,
        (__attribute__((address_space(3))) void*)l, 16, 0, 0);
#else
    *(bf16x8*)l = *(const bf16x8*)g;
#endif
}

// ---------------------------------------------------------------------------
// rope_cs: precompute RoPE cos/sin table CS[t][j] for t<4096, j<64.
// 2MB, L2/L3-resident; replaces per-use cosf/sinf (the m205 trig trap:
// fused transcendental RoPE cost +15us of attn critical-path VALU).
// ---------------------------------------------------------------------------
__global__ void rope_cs(float2* __restrict__ CS, int total)
{
    int idx = blockIdx.x * 256 + threadIdx.x;
    if (idx >= total) return;
    int j = idx & 63;
    int t = idx >> 6;
    const float NEG_LN1E4_64 = -0.14391155806323211f;  // -ln(10000)/64
    float inv_freq = expf(NEG_LN1E4_64 * (float)j);
    float ang = (float)t * inv_freq;
    CS[idx] = make_float2(cosf(ang), sinf(ang));
}

// ---------------------------------------------------------------------------
// cvt_x: fp32 -> bf16, 8 elems/thread, coalesced.
// ---------------------------------------------------------------------------
__global__ void cvt_x(const float* __restrict__ X, bf16* __restrict__ Xb, int total8)
{
    int idx = blockIdx.x * 256 + threadIdx.x;
    if (idx >= total8) return;
    const float* p = X + (size_t)idx * 8;
    f32x4 a = *reinterpret_cast<const f32x4*>(p);
    f32x4 b = *reinterpret_cast<const f32x4*>(p + 4);
    bf16x8 r;
    r[0] = (bf16)a[0]; r[1] = (bf16)a[1]; r[2] = (bf16)a[2]; r[3] = (bf16)a[3];
    r[4] = (bf16)b[0]; r[5] = (bf16)b[1]; r[6] = (bf16)b[2]; r[7] = (bf16)b[3];
    *reinterpret_cast<bf16x8*>(Xb + (size_t)idx * 8) = r;
}

// ---------------------------------------------------------------------------
// cvt_wt3: fused transpose-convert of Wq|Wk|Wv -> Wqkv^T [3072][2048] bf16.
// ---------------------------------------------------------------------------
__global__ void cvt_wt3(const float* __restrict__ Wq, const float* __restrict__ Wk,
                        const float* __restrict__ Wv, bf16* __restrict__ Wt)
{
    __shared__ float t[32][33];
    int bx = blockIdx.x;
    const float* W; int Ncols, nbase;
    if (bx < 64)      { W = Wq; Ncols = 2048; nbase = 0;    }
    else if (bx < 80) { W = Wk; Ncols = 512;  nbase = 2048; bx -= 64; }
    else              { W = Wv; Ncols = 512;  nbase = 2560; bx -= 80; }
    const int n0 = bx * 32, k0 = blockIdx.y * 32;
    const int x = threadIdx.x, y = threadIdx.y;
    #pragma unroll
    for (int i = 0; i < 4; ++i)
        t[y + 8 * i][x] = W[(size_t)(k0 + y + 8 * i) * Ncols + n0 + x];
    __syncthreads();
    #pragma unroll
    for (int i = 0; i < 4; ++i)
        Wt[(size_t)(nbase + n0 + y + 8 * i) * 2048 + k0 + x] = (bf16)t[x][y + 8 * i];
}

// cvt_wt: single-matrix variant (Wo, after QKV GEMM frees its region)
__global__ void cvt_wt(const float* __restrict__ W, bf16* __restrict__ Wt, int Ncols)
{
    __shared__ float t[32][33];
    const int n0 = blockIdx.x * 32, k0 = blockIdx.y * 32;
    const int x = threadIdx.x, y = threadIdx.y;
    #pragma unroll
    for (int i = 0; i < 4; ++i)
        t[y + 8 * i][x] = W[(size_t)(k0 + y + 8 * i) * Ncols + n0 + x];
    __syncthreads();
    #pragma unroll
    for (int i = 0; i < 4; ++i)
        Wt[(size_t)(n0 + y + 8 * i) * 2048 + k0 + x] = (bf16)t[x][y + 8 * i];
}

// ---------------------------------------------------------------------------
// gemm256_qkv: 256Mx192N tile, BK=64, 8 waves (2Mx4N, 128x48 each), grid
// 256 blocks = 1/CU. Counted-vmcnt + T2 source-swizzle + setprio.
// (round-7 structure, measured −5us vs 256x256; unchanged)
// ---------------------------------------------------------------------------
__global__ __launch_bounds__(512, 2) void gemm256_qkv(
    const bf16* __restrict__ A, const bf16* __restrict__ Bt,
    bf16* __restrict__ Qo, bf16* __restrict__ Ko, bf16* __restrict__ Vt,
    int K)
{
    __shared__ __align__(16) bf16 smem[2 * 28672];   // 112 KB: [buf][A|B]

    const int tid  = threadIdx.x;
    const int lane = tid & 63;
    const int wave = tid >> 6;
    const int quad = lane >> 4;
    const int l16  = lane & 15;
    const int wm   = wave >> 2;          // 0..1  (M half, 128 rows)
    const int wn   = wave & 3;           // 0..3  (48 cols each)

    const int m0 = blockIdx.y * 256;
    const int n0 = blockIdx.x * 192;

    int offA[4], offB[3];
    #pragma unroll
    for (int p = 0; p < 4; ++p) {
        int u = p * 512 + tid;
        int row = u >> 3;
        int kc8 = (u & 7) ^ (row & 7);
        offA[p] = (m0 + row) * K + kc8 * 8;
    }
    #pragma unroll
    for (int p = 0; p < 3; ++p) {
        int u = p * 512 + tid;
        int row = u >> 3;                // 0..191
        int kc8 = (u & 7) ^ (row & 7);
        offB[p] = (n0 + row) * K + kc8 * 8;
    }
    const int dstoff = tid * 8;

    const int xv = (l16 & 7) << 4;
    const int c0 = ((quad * 16) ^ xv) >> 1;
    const int c1 = ((64 + quad * 16) ^ xv) >> 1;
    const int rA = (wm * 128 + l16) * 64;
    const int rB = (wn * 48 + l16) * 64;

    f32x4 acc[8][3] = {};
    const int NT = K >> 6;               // 32

    auto stage = [&](int tt, int bsel) {
        bf16* as = smem + bsel * 28672;
        bf16* bs = as + 16384;
        const int koff = tt * 64;
        #pragma unroll
        for (int p = 0; p < 4; ++p)
            ldg_lds16(A + offA[p] + koff, as + p * 4096 + dstoff);
        #pragma unroll
        for (int p = 0; p < 3; ++p)
            ldg_lds16(Bt + offB[p] + koff, bs + p * 4096 + dstoff);
    };

    stage(0, 0);
    stage(1, 1);
    asm volatile("s_waitcnt vmcnt(7)" ::: "memory");
    __builtin_amdgcn_sched_barrier(0);
    __builtin_amdgcn_s_barrier();
    __builtin_amdgcn_sched_barrier(0);

    for (int t = 0; t < NT; ++t) {
        const bf16* As = smem + (t & 1) * 28672;
        const bf16* Bs = As + 16384;

        bf16x8 a0[8], b0[3];
        #pragma unroll
        for (int i = 0; i < 8; ++i)
            a0[i] = *(const bf16x8*)(As + rA + i * 1024 + c0);
        #pragma unroll
        for (int i = 0; i < 3; ++i)
            b0[i] = *(const bf16x8*)(Bs + rB + i * 1024 + c0);

        #pragma unroll
        for (int mi = 0; mi < 8; ++mi)
            #pragma unroll
            for (int ni = 0; ni < 3; ++ni)
                acc[mi][ni] = __builtin_amdgcn_mfma_f32_16x16x32_bf16(
                    a0[mi], b0[ni], acc[mi][ni], 0, 0, 0);

        bf16x8 a1[8], b1[3];
        #pragma unroll
        for (int i = 0; i < 8; ++i)
            a1[i] = *(const bf16x8*)(As + rA + i * 1024 + c1);
        #pragma unroll
        for (int i = 0; i < 3; ++i)
            b1[i] = *(const bf16x8*)(Bs + rB + i * 1024 + c1);

        asm volatile("s_waitcnt lgkmcnt(0)" ::: "memory");
        __builtin_amdgcn_sched_barrier(0);
        __builtin_amdgcn_s_barrier();
        __builtin_amdgcn_sched_barrier(0);

        if (t + 2 < NT) stage(t + 2, t & 1);

        __builtin_amdgcn_s_setprio(1);
        #pragma unroll
        for (int mi = 0; mi < 8; ++mi)
            #pragma unroll
            for (int ni = 0; ni < 3; ++ni)
                acc[mi][ni] = __builtin_amdgcn_mfma_f32_16x16x32_bf16(
                    a1[mi], b1[ni], acc[mi][ni], 0, 0, 0);
        __builtin_amdgcn_s_setprio(0);

        if (t + 2 < NT) {
            asm volatile("s_waitcnt vmcnt(7)" ::: "memory");  // tile t+1 landed
            __builtin_amdgcn_sched_barrier(0);
            __builtin_amdgcn_s_barrier();
            __builtin_amdgcn_sched_barrier(0);
        } else if (t == NT - 2) {
            asm volatile("s_waitcnt vmcnt(0)" ::: "memory");
            __builtin_amdgcn_sched_barrier(0);
            __builtin_amdgcn_s_barrier();
            __builtin_amdgcn_sched_barrier(0);
        }
    }

    #pragma unroll
    for (int mi = 0; mi < 8; ++mi) {
        #pragma unroll
        for (int ni = 0; ni < 3; ++ni) {
            const int row = m0 + wm * 128 + mi * 16 + quad * 4;
            const int col = n0 + wn * 48 + ni * 16 + l16;
            const int cb  = n0 + wn * 48 + ni * 16;    // wave-uniform base
            if (cb < 2048) {            // Q region
                #pragma unroll
                for (int r = 0; r < 4; ++r)
                    Qo[(size_t)(row + r) * 2048 + col] = (bf16)acc[mi][ni][r];
            } else if (cb < 2560) {     // K region
                #pragma unroll
                for (int r = 0; r < 4; ++r)
                    Ko[(size_t)(row + r) * 512 + (col - 2048)] = (bf16)acc[mi][ni][r];
            } else {                    // V region -> transposed Vt[d][t]
                bf16x4 v;
                #pragma unroll
                for (int r = 0; r < 4; ++r) v[r] = (bf16)acc[mi][ni][r];
                *reinterpret_cast<bf16x4*>(&Vt[(size_t)(col - 2560) * 4096 + row]) = v;
            }
        }
    }
}

// ---------------------------------------------------------------------------
// gemm_out: C[4096,2048] = A @ Bt^T, fp32 C. 256Mx128N, BK=64, 8 waves,
// counted-vmcnt pipeline. (proven round 4, unchanged)
// ---------------------------------------------------------------------------
__global__ __launch_bounds__(512, 2) void gemm_out(
    const bf16* __restrict__ A, const bf16* __restrict__ Bt,
    float* __restrict__ C, int K)
{
    __shared__ __align__(16) bf16 smem[2 * 24576];   // 96 KB: [buf][A|B]

    const int tid  = threadIdx.x;
    const int lane = tid & 63;
    const int wave = tid >> 6;
    const int quad = lane >> 4;
    const int l16  = lane & 15;
    const int wm   = wave >> 1;
    const int wn   = wave & 1;

    const int m0 = blockIdx.y * 256;
    const int n0 = blockIdx.x * 128;

    int offA[4], offB[2];
    #pragma unroll
    for (int p = 0; p < 4; ++p) {
        int u = p * 512 + tid;
        int row = u >> 3;
        int kc8 = (u & 7) ^ (row & 7);
        offA[p] = (m0 + row) * K + kc8 * 8;
    }
    #pragma unroll
    for (int p = 0; p < 2; ++p) {
        int u = p * 512 + tid;
        int row = u >> 3;
        int kc8 = (u & 7) ^ (row & 7);
        offB[p] = (n0 + row) * K + kc8 * 8;
    }
    const int dstoff = tid * 8;

    const int xv = (l16 & 7) << 4;
    const int c0 = ((quad * 16) ^ xv) >> 1;
    const int c1 = ((64 + quad * 16) ^ xv) >> 1;
    const int rA = (wm * 64 + l16) * 64;
    const int rB = (wn * 64 + l16) * 64;

    f32x4 acc[4][4] = {};
    const int NT = K >> 6;

    auto stage = [&](int tt, int bsel) {
        bf16* as = smem + bsel * 24576;
        bf16* bs = as + 16384;
        const int koff = tt * 64;
        #pragma unroll
        for (int p = 0; p < 4; ++p)
            ldg_lds16(A + offA[p] + koff, as + p * 4096 + dstoff);
        #pragma unroll
        for (int p = 0; p < 2; ++p)
            ldg_lds16(Bt + offB[p] + koff, bs + p * 4096 + dstoff);
    };

    stage(0, 0);
    stage(1, 1);
    asm volatile("s_waitcnt vmcnt(6)" ::: "memory");
    __builtin_amdgcn_sched_barrier(0);
    __builtin_amdgcn_s_barrier();
    __builtin_amdgcn_sched_barrier(0);

    for (int t = 0; t < NT; ++t) {
        const bf16* As = smem + (t & 1) * 24576;
        const bf16* Bs = As + 16384;

        bf16x8 a0[4], b0[4];
        #pragma unroll
        for (int i = 0; i < 4; ++i)
            a0[i] = *(const bf16x8*)(As + rA + i * 1024 + c0);
        #pragma unroll
        for (int i = 0; i < 4; ++i)
            b0[i] = *(const bf16x8*)(Bs + rB + i * 1024 + c0);

        #pragma unroll
        for (int mi = 0; mi < 4; ++mi)
            #pragma unroll
            for (int ni = 0; ni < 4; ++ni)
                acc[mi][ni] = __builtin_amdgcn_mfma_f32_16x16x32_bf16(
                    a0[mi], b0[ni], acc[mi][ni], 0, 0, 0);

        bf16x8 a1[4], b1[4];
        #pragma unroll
        for (int i = 0; i < 4; ++i)
            a1[i] = *(const bf16x8*)(As + rA + i * 1024 + c1);
        #pragma unroll
        for (int i = 0; i < 4; ++i)
            b1[i] = *(const bf16x8*)(Bs + rB + i * 1024 + c1);

        asm volatile("s_waitcnt lgkmcnt(0)" ::: "memory");
        __builtin_amdgcn_sched_barrier(0);
        __builtin_amdgcn_s_barrier();
        __builtin_amdgcn_sched_barrier(0);

        if (t + 2 < NT) stage(t + 2, t & 1);

        __builtin_amdgcn_s_setprio(1);
        #pragma unroll
        for (int mi = 0; mi < 4; ++mi)
            #pragma unroll
            for (int ni = 0; ni < 4; ++ni)
                acc[mi][ni] = __builtin_amdgcn_mfma_f32_16x16x32_bf16(
                    a1[mi], b1[ni], acc[mi][ni], 0, 0, 0);
        __builtin_amdgcn_s_setprio(0);

        if (t + 2 < NT) {
            asm volatile("s_waitcnt vmcnt(6)" ::: "memory");
            __builtin_amdgcn_sched_barrier(0);
            __builtin_amdgcn_s_barrier();
            __builtin_amdgcn_sched_barrier(0);
        } else if (t == NT - 2) {
            asm volatile("s_waitcnt vmcnt(0)" ::: "memory");
            __builtin_amdgcn_sched_barrier(0);
            __builtin_amdgcn_s_barrier();
            __builtin_amdgcn_sched_barrier(0);
        }
    }

    #pragma unroll
    for (int mi = 0; mi < 4; ++mi) {
        #pragma unroll
        for (int ni = 0; ni < 4; ++ni) {
            const int row = m0 + wm * 64 + mi * 16 + quad * 4;
            const int col = n0 + wn * 64 + ni * 16 + l16;
            #pragma unroll
            for (int r = 0; r < 4; ++r)
                C[(size_t)(row + r) * 2048 + col] = acc[mi][ni][r];
        }
    }
}

// ---------------------------------------------------------------------------
// rope_k: RoPE for K [T,4,128] via the CS table (no transcendentals).
// ---------------------------------------------------------------------------
__global__ void rope_k(const float2* __restrict__ CS, bf16* __restrict__ Kb,
                       int total)
{
    int idx = blockIdx.x * 256 + threadIdx.x;
    if (idx >= total) return;
    int j  = idx & 63;
    int th = idx >> 6;
    int t  = th >> 2;

    bf16* p = Kb + (size_t)th * 128;
    float2 cs = CS[t * 64 + j];
    float q0 = (float)p[j], q1 = (float)p[j + 64];
    p[j]      = (bf16)(q0 * cs.x - q1 * cs.y);
    p[j + 64] = (bf16)(q1 * cs.x + q0 * cs.y);
}

// ---------------------------------------------------------------------------
// attn_v11: flash attention, sliding window 1024, causal, GQA.
// = v7's proven double-buffered global_load_lds + counted-vmcnt pipeline
// + packed swizzled Pl (stride 64) + wave-uniform fast path (the v9 combo,
//   A/B-isolated at −5.4us via v10)
// + Q-RoPE fused via CS TABLE lookup (16 dwordx2 + 32 FMA per thread) —
//   replaces the transcendental fusion that cost +15us (v10 lesson).
// ---------------------------------------------------------------------------
__global__ __launch_bounds__(256) void attn_v11(
    const bf16* __restrict__ Q, const bf16* __restrict__ K,
    const bf16* __restrict__ Vt, bf16* __restrict__ Y,
    const float2* __restrict__ CS)
{
    const float scale = 0.08838834764831845f;  // 1/sqrt(128)

    __shared__ __align__(16) bf16 Ks[2 * 64 * 128];  // [buf][kk][128d], chunk^=(kk&15)
    __shared__ __align__(16) bf16 Vs[2 * 128 * 64];  // [buf][d][64k],   chunk^=(d&7)
    __shared__ __align__(16) bf16 Pl[4][16 * 64];    // [row][64k],      chunk^=(row&7)

    const int tid  = threadIdx.x;
    const int lane = tid & 63;
    const int wave = tid >> 6;
    const int quad = lane >> 4;
    const int l16  = lane & 15;

    const int i0  = (gridDim.x - 1 - blockIdx.x) * 64;   // long blocks first
    const int h   = blockIdx.y;
    const int kvh = h >> 2;
    const int q0  = i0 + wave * 16;
    bf16* Plw = Pl[wave];

    const int ks = (i0 >= 1024) ? (i0 - 1024) : 0;
    const int nsteps = (i0 + 64 - ks) >> 6;

    auto stage = [&](int tt, int bsel) {
        const int k0s = ks + tt * 64;
        bf16* kd = Ks + bsel * 8192;
        bf16* vd = Vs + bsel * 8192;
        #pragma unroll
        for (int p = 0; p < 4; ++p) {
            int u = p * 256 + tid;
            int kk = u >> 4, sc = u & 15;
            ldg_lds16(K + (size_t)(k0s + kk) * 512 + kvh * 128 + (sc ^ (kk & 15)) * 8,
                      kd + u * 8);
        }
        #pragma unroll
        for (int p = 0; p < 4; ++p) {
            int u = p * 256 + tid;
            int d = u >> 3, sc = u & 7;
            ldg_lds16(Vt + (size_t)(kvh * 128 + d) * 4096 + k0s + (sc ^ (d & 7)) * 8,
                      vd + u * 8);
        }
    };

    // Q + cos/sin table loads first (oldest vmem ops); staging issues after,
    // so the RoPE math's data wait leaves the 16 staging loads in flight.
    bf16x8 qr_[4];
    float2 csv[16];
    {
        const bf16* qp = Q + (size_t)(q0 + l16) * 2048 + h * 128 + quad * 8;
        #pragma unroll
        for (int c = 0; c < 4; ++c)
            qr_[c] = *reinterpret_cast<const bf16x8*>(qp + c * 32);
        const float2* csp = CS + (size_t)(q0 + l16) * 64 + quad * 8;
        #pragma unroll
        for (int c = 0; c < 2; ++c)
            #pragma unroll
            for (int i = 0; i < 8; ++i)
                csv[c * 8 + i] = csp[c * 32 + i];
    }

    // prologue: stage tiles 0 and 1 (tile-1 rows always < 4096 -> in-bounds
    // even when nsteps==1; data simply unused then).
    stage(0, 0);
    stage(1, 1);

    // fused Q-RoPE via table (32 FMA, no transcendentals)
    bf16x8 qf[4];
    #pragma unroll
    for (int c = 0; c < 2; ++c) {
        #pragma unroll
        for (int i = 0; i < 8; ++i) {
            float cs_ = csv[c * 8 + i].x, sn = csv[c * 8 + i].y;
            float a = (float)qr_[c][i], b = (float)qr_[c + 2][i];
            qf[c][i]     = (bf16)(a * cs_ - b * sn);
            qf[c + 2][i] = (bf16)(b * cs_ + a * sn);
        }
    }

    f32x4 o[8] = {};
    float lsum[4] = {0.f, 0.f, 0.f, 0.f};

    asm volatile("s_waitcnt vmcnt(8)" ::: "memory");   // tile 0 landed
    __builtin_amdgcn_sched_barrier(0);
    __builtin_amdgcn_s_barrier();
    __builtin_amdgcn_sched_barrier(0);

    for (int t = 0; t < nsteps; ++t) {
        const int b  = t & 1;
        const int k0 = ks + t * 64;
        const bf16* Kb = Ks + b * 8192;
        const bf16* Vb = Vs + b * 8192;

        // S = Q K^T, four 16-key tiles (B-frags from swizzled Ks)
        f32x4 s[4];
        __builtin_amdgcn_s_setprio(1);
        #pragma unroll
        for (int kh = 0; kh < 4; ++kh) {
            const int kk = kh * 16 + l16;
            f32x4 sv = {};
            #pragma unroll
            for (int c = 0; c < 4; ++c) {
                bf16x8 kf = *reinterpret_cast<const bf16x8*>(
                    &Kb[kk * 128 + (((c * 4 + quad) ^ (kk & 15)) * 8)]);
                sv = __builtin_amdgcn_mfma_f32_16x16x32_bf16(qf[c], kf, sv, 0, 0, 0);
            }
            s[kh] = sv;
        }
        __builtin_amdgcn_s_setprio(0);

        // P = exp(mask(S*scale)), fixed max 0; packed swizzled Pl write.
        // Wave-uniform fast path: interior steps need no masking at all.
        const bool full = (k0 + 63 <= q0) && (q0 + 15 - k0 < 1024);
        if (full) {
            #pragma unroll
            for (int kh = 0; kh < 4; ++kh) {
                #pragma unroll
                for (int r = 0; r < 4; ++r) {
                    float pv = __expf(s[kh][r] * scale);
                    lsum[r] += pv;
                    const int row = quad * 4 + r;
                    const int idx = row * 64 +
                        ((((kh * 2 + (l16 >> 3)) ^ (row & 7)) << 3) | (l16 & 7));
                    Plw[idx] = (bf16)pv;
                }
            }
        } else {
            #pragma unroll
            for (int kh = 0; kh < 4; ++kh) {
                const int key = k0 + kh * 16 + l16;
                #pragma unroll
                for (int r = 0; r < 4; ++r) {
                    const int qrow = q0 + quad * 4 + r;
                    bool ok = (unsigned)(qrow - key) < 1024u;   // causal & window
                    float pv = ok ? __expf(s[kh][r] * scale) : 0.f;
                    lsum[r] += pv;
                    const int row = quad * 4 + r;
                    const int idx = row * 64 +
                        ((((kh * 2 + (l16 >> 3)) ^ (row & 7)) << 3) | (l16 & 7));
                    Plw[idx] = (bf16)pv;
                }
            }
        }

        // PV: P (A-frags, packed swizzled Pl) x V (B-frags, swizzled Vs)
        bf16x8 pf0 = *reinterpret_cast<const bf16x8*>(
            &Plw[l16 * 64 + ((quad ^ (l16 & 7)) << 3)]);
        bf16x8 pf1 = *reinterpret_cast<const bf16x8*>(
            &Plw[l16 * 64 + (((4 + quad) ^ (l16 & 7)) << 3)]);
        __builtin_amdgcn_s_setprio(1);
        #pragma unroll
        for (int n = 0; n < 8; ++n) {
            const int d = n * 16 + l16;
            bf16x8 v0 = *reinterpret_cast<const bf16x8*>(
                &Vb[d * 64 + (((quad) ^ (d & 7)) * 8)]);
            bf16x8 v1 = *reinterpret_cast<const bf16x8*>(
                &Vb[d * 64 + (((4 + quad) ^ (d & 7)) * 8)]);
            o[n] = __builtin_amdgcn_mfma_f32_16x16x32_bf16(pf0, v0, o[n], 0, 0, 0);
            o[n] = __builtin_amdgcn_mfma_f32_16x16x32_bf16(pf1, v1, o[n], 0, 0, 0);
        }
        __builtin_amdgcn_s_setprio(0);

        // ---- pipeline boundary: all reads of buf b done -> restage it
        asm volatile("s_waitcnt lgkmcnt(0)" ::: "memory");
        __builtin_amdgcn_sched_barrier(0);
        __builtin_amdgcn_s_barrier();
        __builtin_amdgcn_sched_barrier(0);

        if (t + 2 < nsteps) {
            stage(t + 2, b);
            asm volatile("s_waitcnt vmcnt(8)" ::: "memory");  // tile t+1 landed
        } else {
            asm volatile("s_waitcnt vmcnt(0)" ::: "memory");  // drain tail
        }
        __builtin_amdgcn_sched_barrier(0);
        __builtin_amdgcn_s_barrier();
        __builtin_amdgcn_sched_barrier(0);
    }

    // final: reduce l over the 16 lanes of each row (once), normalize, store
    #pragma unroll
    for (int r = 0; r < 4; ++r) {
        #pragma unroll
        for (int off = 1; off < 16; off <<= 1)
            lsum[r] += __shfl_xor(lsum[r], off, 64);
    }
    #pragma unroll
    for (int r = 0; r < 4; ++r) {
        int row = q0 + quad * 4 + r;
        float inv = (lsum[r] > 0.f) ? 1.f / lsum[r] : 0.f;
        #pragma unroll
        for (int n = 0; n < 8; ++n)
            Y[(size_t)row * 2048 + h * 128 + n * 16 + l16] = (bf16)(o[n][r] * inv);
    }
}

// ---------------------------------------------------------------------------
extern "C" void kernel_launch(void* const* d_in, const int* in_sizes, int n_in,
                              void* d_out, int out_size, void* d_ws, size_t ws_size,
                              hipStream_t stream)
{
    const float* x  = (const float*)d_in[0];
    const float* Wq = (const float*)d_in[1];
    const float* Wk = (const float*)d_in[2];
    const float* Wv = (const float*)d_in[3];
    const float* Wo = (const float*)d_in[4];
    float* out = (float*)d_out;

    const int T = 4096, DIM = 2048;

    // d_out (32MB fp32) hosts bf16 intermediates, all dead before final GEMM:
    //   [0,16M) Qb [T,2048] | [16M,20M) Kb [T,512] | [20M,24M) Vt [512][T]
    //   [24M,26M) CS table [4096][64] float2 (dead before gemm_out)
    char* po = (char*)d_out;
    bf16* Qb  = (bf16*)(po);
    bf16* Kb  = (bf16*)(po + (16u << 20));
    bf16* Vtb = (bf16*)(po + (20u << 20));
    float2* CS = (float2*)(po + (24u << 20));

    // ws (peak 28MB): [0,16M) xb -> later Yb ; [16M,28M) Wqkv^T -> later Wo^T
    char* ws = (char*)d_ws;
    bf16* xb    = (bf16*)(ws);
    bf16* Wqkvt = (bf16*)(ws + (16u << 20));
    bf16* Yb    = (bf16*)(ws);                 // reuses xb (dead after QKV GEMM)
    bf16* Wot   = (bf16*)(ws + (16u << 20));   // reuses Wqkv^T (dead after QKV GEMM)

    // 0. RoPE cos/sin table (2MB, L2/L3-resident)
    rope_cs<<<dim3(T * 64 / 256), 256, 0, stream>>>(CS, T * 64);

    // 1. convert x -> bf16
    cvt_x<<<dim3(T * DIM / 8 / 256), 256, 0, stream>>>(x, xb, T * DIM / 8);

    // 2. fused transpose-convert Wq|Wk|Wv -> Wqkv^T [3072][2048]
    dim3 tb(32, 8);
    cvt_wt3<<<dim3(96, 64), tb, 0, stream>>>(Wq, Wk, Wv, Wqkvt);

    // 3. fused QKV GEMM (256x192 tiles -> 256 blocks, full CU fill)
    gemm256_qkv<<<dim3(3072 / 192, T / 256), 512, 0, stream>>>(
        xb, Wqkvt, Qb, Kb, Vtb, DIM);

    // 4. Wo^T (after QKV GEMM frees the region)
    cvt_wt<<<dim3(2048 / 32, 64), tb, 0, stream>>>(Wo, Wot, 2048);

    // 5. RoPE on K only (Q-RoPE fused into attn via CS table)
    int ktot = T * 4 * 64;
    rope_k<<<(ktot + 255) / 256, 256, 0, stream>>>(CS, Kb, ktot);

    // 6. attention (v11 = v7 pipeline + packed Pl + fastpath + table Q-RoPE)
    attn_v11<<<dim3(T / 64, 16), 256, 0, stream>>>(Qb, Kb, Vtb, Yb, CS);

    // 7. output projection (256x128 deep-pipelined): -> out (fp32)
    gemm_out<<<dim3(2048 / 128, T / 256), 512, 0, stream>>>(
        Yb, Wot, out, DIM);
}

// Round 9
// 271.878 us; speedup vs baseline: 1.0639x; 1.0251x over previous
//
#include <hip/hip_runtime.h>
#include <math.h>

typedef __bf16 bf16;
typedef __bf16 bf16x8 __attribute__((ext_vector_type(8)));
typedef __bf16 bf16x4 __attribute__((ext_vector_type(4)));
typedef float f32x4 __attribute__((ext_vector_type(4)));

// ---------------------------------------------------------------------------
// async global->LDS 16B (direct-to-shared DMA). LDS dest must be
// wave-uniform base + lane*16 — all staging maps below guarantee that.
// ---------------------------------------------------------------------------
__device__ __forceinline__ void ldg_lds16(const bf16* g, bf16* l) {
#if __has_builtin(__builtin_amdgcn_global_load_lds)
    __builtin_amdgcn_global_load_lds(
        (const __attribute__((address_space(1))) void*)g,
        (__attribute__((address_space(3))) void*)l, 16, 0, 0);
#else
    *(bf16x8*)l = *(const bf16x8*)g;
#endif
}

// ---------------------------------------------------------------------------
// fused_pre: rope_cs (blocks [0,1024)) + cvt_x (blocks [1024,5120)) +
// cvt_wt3 (blocks [5120,11264)). All parts independent; branch is
// block-uniform. Replaces 3 launches with 1 (launch-gap elimination).
// ---------------------------------------------------------------------------
__global__ void fused_pre(const float* __restrict__ X,
                          const float* __restrict__ Wq,
                          const float* __restrict__ Wk,
                          const float* __restrict__ Wv,
                          bf16* __restrict__ Xb,
                          bf16* __restrict__ Wt,
                          float2* __restrict__ CS)
{
    __shared__ float t[32][33];
    const int tid = threadIdx.x;
    int blk = blockIdx.x;

    if (blk < 1024) {
        // ---- rope_cs: CS[t][j], t<4096, j<64 (2MB, L2/L3-resident)
        int idx = blk * 256 + tid;
        int j = idx & 63;
        int tt = idx >> 6;
        const float NEG_LN1E4_64 = -0.14391155806323211f;  // -ln(10000)/64
        float inv_freq = expf(NEG_LN1E4_64 * (float)j);
        float ang = (float)tt * inv_freq;
        CS[idx] = make_float2(cosf(ang), sinf(ang));
        return;
    }
    blk -= 1024;
    if (blk < 4096) {
        // ---- cvt_x: fp32 -> bf16, 8 elems/thread (total8 = 1048576)
        int idx = blk * 256 + tid;
        const float* p = X + (size_t)idx * 8;
        f32x4 a = *reinterpret_cast<const f32x4*>(p);
        f32x4 b = *reinterpret_cast<const f32x4*>(p + 4);
        bf16x8 r;
        r[0] = (bf16)a[0]; r[1] = (bf16)a[1]; r[2] = (bf16)a[2]; r[3] = (bf16)a[3];
        r[4] = (bf16)b[0]; r[5] = (bf16)b[1]; r[6] = (bf16)b[2]; r[7] = (bf16)b[3];
        *reinterpret_cast<bf16x8*>(Xb + (size_t)idx * 8) = r;
        return;
    }
    blk -= 4096;
    // ---- cvt_wt3: transpose-convert Wq|Wk|Wv -> Wt[3072][2048]
    int bx = blk % 96;
    int k0 = (blk / 96) * 32;
    const float* W; int Ncols, nbase;
    if (bx < 64)      { W = Wq; Ncols = 2048; nbase = 0;    }
    else if (bx < 80) { W = Wk; Ncols = 512;  nbase = 2048; bx -= 64; }
    else              { W = Wv; Ncols = 512;  nbase = 2560; bx -= 80; }
    const int n0 = bx * 32;
    const int x = tid & 31, y = tid >> 5;
    #pragma unroll
    for (int i = 0; i < 4; ++i)
        t[y + 8 * i][x] = W[(size_t)(k0 + y + 8 * i) * Ncols + n0 + x];
    __syncthreads();
    #pragma unroll
    for (int i = 0; i < 4; ++i)
        Wt[(size_t)(nbase + n0 + y + 8 * i) * 2048 + k0 + x] = (bf16)t[x][y + 8 * i];
}

// ---------------------------------------------------------------------------
// fused_mid: cvt_wt(Wo) (blocks [0,4096)) + rope_k (blocks [4096,8192)).
// Both depend only on gemm256_qkv (Wo^T reuses the freed Wqkvt region;
// rope_k updates Kb in place). Replaces 2 launches with 1.
// ---------------------------------------------------------------------------
__global__ void fused_mid(const float* __restrict__ Wo,
                          bf16* __restrict__ Wot,
                          const float2* __restrict__ CS,
                          bf16* __restrict__ Kb)
{
    __shared__ float t[32][33];
    const int tid = threadIdx.x;
    int blk = blockIdx.x;

    if (blk < 4096) {
        // ---- cvt_wt: Wo [2048][2048] fp32 -> Wot [2048][2048] bf16 (transp)
        const int n0 = (blk & 63) * 32, k0 = (blk >> 6) * 32;
        const int x = tid & 31, y = tid >> 5;
        #pragma unroll
        for (int i = 0; i < 4; ++i)
            t[y + 8 * i][x] = Wo[(size_t)(k0 + y + 8 * i) * 2048 + n0 + x];
        __syncthreads();
        #pragma unroll
        for (int i = 0; i < 4; ++i)
            Wot[(size_t)(n0 + y + 8 * i) * 2048 + k0 + x] = (bf16)t[x][y + 8 * i];
        return;
    }
    blk -= 4096;
    // ---- rope_k via CS table (total = 1048576 threads)
    int idx = blk * 256 + tid;
    int j  = idx & 63;
    int th = idx >> 6;
    int tt = th >> 2;

    bf16* p = Kb + (size_t)th * 128;
    float2 cs = CS[tt * 64 + j];
    float q0 = (float)p[j], q1 = (float)p[j + 64];
    p[j]      = (bf16)(q0 * cs.x - q1 * cs.y);
    p[j + 64] = (bf16)(q1 * cs.x + q0 * cs.y);
}

// ---------------------------------------------------------------------------
// gemm256_qkv: 256Mx192N tile, BK=64, 8 waves (2Mx4N, 128x48 each), grid
// 256 blocks = 1/CU. Counted-vmcnt + T2 source-swizzle + setprio.
// (round-7 structure, unchanged)
// ---------------------------------------------------------------------------
__global__ __launch_bounds__(512, 2) void gemm256_qkv(
    const bf16* __restrict__ A, const bf16* __restrict__ Bt,
    bf16* __restrict__ Qo, bf16* __restrict__ Ko, bf16* __restrict__ Vt,
    int K)
{
    __shared__ __align__(16) bf16 smem[2 * 28672];   // 112 KB: [buf][A|B]

    const int tid  = threadIdx.x;
    const int lane = tid & 63;
    const int wave = tid >> 6;
    const int quad = lane >> 4;
    const int l16  = lane & 15;
    const int wm   = wave >> 2;          // 0..1  (M half, 128 rows)
    const int wn   = wave & 3;           // 0..3  (48 cols each)

    const int m0 = blockIdx.y * 256;
    const int n0 = blockIdx.x * 192;

    int offA[4], offB[3];
    #pragma unroll
    for (int p = 0; p < 4; ++p) {
        int u = p * 512 + tid;
        int row = u >> 3;
        int kc8 = (u & 7) ^ (row & 7);
        offA[p] = (m0 + row) * K + kc8 * 8;
    }
    #pragma unroll
    for (int p = 0; p < 3; ++p) {
        int u = p * 512 + tid;
        int row = u >> 3;                // 0..191
        int kc8 = (u & 7) ^ (row & 7);
        offB[p] = (n0 + row) * K + kc8 * 8;
    }
    const int dstoff = tid * 8;

    const int xv = (l16 & 7) << 4;
    const int c0 = ((quad * 16) ^ xv) >> 1;
    const int c1 = ((64 + quad * 16) ^ xv) >> 1;
    const int rA = (wm * 128 + l16) * 64;
    const int rB = (wn * 48 + l16) * 64;

    f32x4 acc[8][3] = {};
    const int NT = K >> 6;               // 32

    auto stage = [&](int tt, int bsel) {
        bf16* as = smem + bsel * 28672;
        bf16* bs = as + 16384;
        const int koff = tt * 64;
        #pragma unroll
        for (int p = 0; p < 4; ++p)
            ldg_lds16(A + offA[p] + koff, as + p * 4096 + dstoff);
        #pragma unroll
        for (int p = 0; p < 3; ++p)
            ldg_lds16(Bt + offB[p] + koff, bs + p * 4096 + dstoff);
    };

    stage(0, 0);
    stage(1, 1);
    asm volatile("s_waitcnt vmcnt(7)" ::: "memory");
    __builtin_amdgcn_sched_barrier(0);
    __builtin_amdgcn_s_barrier();
    __builtin_amdgcn_sched_barrier(0);

    for (int t = 0; t < NT; ++t) {
        const bf16* As = smem + (t & 1) * 28672;
        const bf16* Bs = As + 16384;

        bf16x8 a0[8], b0[3];
        #pragma unroll
        for (int i = 0; i < 8; ++i)
            a0[i] = *(const bf16x8*)(As + rA + i * 1024 + c0);
        #pragma unroll
        for (int i = 0; i < 3; ++i)
            b0[i] = *(const bf16x8*)(Bs + rB + i * 1024 + c0);

        #pragma unroll
        for (int mi = 0; mi < 8; ++mi)
            #pragma unroll
            for (int ni = 0; ni < 3; ++ni)
                acc[mi][ni] = __builtin_amdgcn_mfma_f32_16x16x32_bf16(
                    a0[mi], b0[ni], acc[mi][ni], 0, 0, 0);

        bf16x8 a1[8], b1[3];
        #pragma unroll
        for (int i = 0; i < 8; ++i)
            a1[i] = *(const bf16x8*)(As + rA + i * 1024 + c1);
        #pragma unroll
        for (int i = 0; i < 3; ++i)
            b1[i] = *(const bf16x8*)(Bs + rB + i * 1024 + c1);

        asm volatile("s_waitcnt lgkmcnt(0)" ::: "memory");
        __builtin_amdgcn_sched_barrier(0);
        __builtin_amdgcn_s_barrier();
        __builtin_amdgcn_sched_barrier(0);

        if (t + 2 < NT) stage(t + 2, t & 1);

        __builtin_amdgcn_s_setprio(1);
        #pragma unroll
        for (int mi = 0; mi < 8; ++mi)
            #pragma unroll
            for (int ni = 0; ni < 3; ++ni)
                acc[mi][ni] = __builtin_amdgcn_mfma_f32_16x16x32_bf16(
                    a1[mi], b1[ni], acc[mi][ni], 0, 0, 0);
        __builtin_amdgcn_s_setprio(0);

        if (t + 2 < NT) {
            asm volatile("s_waitcnt vmcnt(7)" ::: "memory");  // tile t+1 landed
            __builtin_amdgcn_sched_barrier(0);
            __builtin_amdgcn_s_barrier();
            __builtin_amdgcn_sched_barrier(0);
        } else if (t == NT - 2) {
            asm volatile("s_waitcnt vmcnt(0)" ::: "memory");
            __builtin_amdgcn_sched_barrier(0);
            __builtin_amdgcn_s_barrier();
            __builtin_amdgcn_sched_barrier(0);
        }
    }

    #pragma unroll
    for (int mi = 0; mi < 8; ++mi) {
        #pragma unroll
        for (int ni = 0; ni < 3; ++ni) {
            const int row = m0 + wm * 128 + mi * 16 + quad * 4;
            const int col = n0 + wn * 48 + ni * 16 + l16;
            const int cb  = n0 + wn * 48 + ni * 16;    // wave-uniform base
            if (cb < 2048) {            // Q region
                #pragma unroll
                for (int r = 0; r < 4; ++r)
                    Qo[(size_t)(row + r) * 2048 + col] = (bf16)acc[mi][ni][r];
            } else if (cb < 2560) {     // K region
                #pragma unroll
                for (int r = 0; r < 4; ++r)
                    Ko[(size_t)(row + r) * 512 + (col - 2048)] = (bf16)acc[mi][ni][r];
            } else {                    // V region -> transposed Vt[d][t]
                bf16x4 v;
                #pragma unroll
                for (int r = 0; r < 4; ++r) v[r] = (bf16)acc[mi][ni][r];
                *reinterpret_cast<bf16x4*>(&Vt[(size_t)(col - 2560) * 4096 + row]) = v;
            }
        }
    }
}

// ---------------------------------------------------------------------------
// gemm_out: C[4096,2048] = A @ Bt^T, fp32 C. 256Mx128N, BK=64, 8 waves,
// counted-vmcnt pipeline. (proven round 4, unchanged)
// ---------------------------------------------------------------------------
__global__ __launch_bounds__(512, 2) void gemm_out(
    const bf16* __restrict__ A, const bf16* __restrict__ Bt,
    float* __restrict__ C, int K)
{
    __shared__ __align__(16) bf16 smem[2 * 24576];   // 96 KB: [buf][A|B]

    const int tid  = threadIdx.x;
    const int lane = tid & 63;
    const int wave = tid >> 6;
    const int quad = lane >> 4;
    const int l16  = lane & 15;
    const int wm   = wave >> 1;
    const int wn   = wave & 1;

    const int m0 = blockIdx.y * 256;
    const int n0 = blockIdx.x * 128;

    int offA[4], offB[2];
    #pragma unroll
    for (int p = 0; p < 4; ++p) {
        int u = p * 512 + tid;
        int row = u >> 3;
        int kc8 = (u & 7) ^ (row & 7);
        offA[p] = (m0 + row) * K + kc8 * 8;
    }
    #pragma unroll
    for (int p = 0; p < 2; ++p) {
        int u = p * 512 + tid;
        int row = u >> 3;
        int kc8 = (u & 7) ^ (row & 7);
        offB[p] = (n0 + row) * K + kc8 * 8;
    }
    const int dstoff = tid * 8;

    const int xv = (l16 & 7) << 4;
    const int c0 = ((quad * 16) ^ xv) >> 1;
    const int c1 = ((64 + quad * 16) ^ xv) >> 1;
    const int rA = (wm * 64 + l16) * 64;
    const int rB = (wn * 64 + l16) * 64;

    f32x4 acc[4][4] = {};
    const int NT = K >> 6;

    auto stage = [&](int tt, int bsel) {
        bf16* as = smem + bsel * 24576;
        bf16* bs = as + 16384;
        const int koff = tt * 64;
        #pragma unroll
        for (int p = 0; p < 4; ++p)
            ldg_lds16(A + offA[p] + koff, as + p * 4096 + dstoff);
        #pragma unroll
        for (int p = 0; p < 2; ++p)
            ldg_lds16(Bt + offB[p] + koff, bs + p * 4096 + dstoff);
    };

    stage(0, 0);
    stage(1, 1);
    asm volatile("s_waitcnt vmcnt(6)" ::: "memory");
    __builtin_amdgcn_sched_barrier(0);
    __builtin_amdgcn_s_barrier();
    __builtin_amdgcn_sched_barrier(0);

    for (int t = 0; t < NT; ++t) {
        const bf16* As = smem + (t & 1) * 24576;
        const bf16* Bs = As + 16384;

        bf16x8 a0[4], b0[4];
        #pragma unroll
        for (int i = 0; i < 4; ++i)
            a0[i] = *(const bf16x8*)(As + rA + i * 1024 + c0);
        #pragma unroll
        for (int i = 0; i < 4; ++i)
            b0[i] = *(const bf16x8*)(Bs + rB + i * 1024 + c0);

        #pragma unroll
        for (int mi = 0; mi < 4; ++mi)
            #pragma unroll
            for (int ni = 0; ni < 4; ++ni)
                acc[mi][ni] = __builtin_amdgcn_mfma_f32_16x16x32_bf16(
                    a0[mi], b0[ni], acc[mi][ni], 0, 0, 0);

        bf16x8 a1[4], b1[4];
        #pragma unroll
        for (int i = 0; i < 4; ++i)
            a1[i] = *(const bf16x8*)(As + rA + i * 1024 + c1);
        #pragma unroll
        for (int i = 0; i < 4; ++i)
            b1[i] = *(const bf16x8*)(Bs + rB + i * 1024 + c1);

        asm volatile("s_waitcnt lgkmcnt(0)" ::: "memory");
        __builtin_amdgcn_sched_barrier(0);
        __builtin_amdgcn_s_barrier();
        __builtin_amdgcn_sched_barrier(0);

        if (t + 2 < NT) stage(t + 2, t & 1);

        __builtin_amdgcn_s_setprio(1);
        #pragma unroll
        for (int mi = 0; mi < 4; ++mi)
            #pragma unroll
            for (int ni = 0; ni < 4; ++ni)
                acc[mi][ni] = __builtin_amdgcn_mfma_f32_16x16x32_bf16(
                    a1[mi], b1[ni], acc[mi][ni], 0, 0, 0);
        __builtin_amdgcn_s_setprio(0);

        if (t + 2 < NT) {
            asm volatile("s_waitcnt vmcnt(6)" ::: "memory");
            __builtin_amdgcn_sched_barrier(0);
            __builtin_amdgcn_s_barrier();
            __builtin_amdgcn_sched_barrier(0);
        } else if (t == NT - 2) {
            asm volatile("s_waitcnt vmcnt(0)" ::: "memory");
            __builtin_amdgcn_sched_barrier(0);
            __builtin_amdgcn_s_barrier();
            __builtin_amdgcn_sched_barrier(0);
        }
    }

    #pragma unroll
    for (int mi = 0; mi < 4; ++mi) {
        #pragma unroll
        for (int ni = 0; ni < 4; ++ni) {
            const int row = m0 + wm * 64 + mi * 16 + quad * 4;
            const int col = n0 + wn * 64 + ni * 16 + l16;
            #pragma unroll
            for (int r = 0; r < 4; ++r)
                C[(size_t)(row + r) * 2048 + col] = acc[mi][ni][r];
        }
    }
}

// ---------------------------------------------------------------------------
// attn_v11: flash attention, sliding window 1024, causal, GQA.
// (round-8 structure, measured 72.9us, unchanged)
// ---------------------------------------------------------------------------
__global__ __launch_bounds__(256) void attn_v11(
    const bf16* __restrict__ Q, const bf16* __restrict__ K,
    const bf16* __restrict__ Vt, bf16* __restrict__ Y,
    const float2* __restrict__ CS)
{
    const float scale = 0.08838834764831845f;  // 1/sqrt(128)

    __shared__ __align__(16) bf16 Ks[2 * 64 * 128];  // [buf][kk][128d], chunk^=(kk&15)
    __shared__ __align__(16) bf16 Vs[2 * 128 * 64];  // [buf][d][64k],   chunk^=(d&7)
    __shared__ __align__(16) bf16 Pl[4][16 * 64];    // [row][64k],      chunk^=(row&7)

    const int tid  = threadIdx.x;
    const int lane = tid & 63;
    const int wave = tid >> 6;
    const int quad = lane >> 4;
    const int l16  = lane & 15;

    const int i0  = (gridDim.x - 1 - blockIdx.x) * 64;   // long blocks first
    const int h   = blockIdx.y;
    const int kvh = h >> 2;
    const int q0  = i0 + wave * 16;
    bf16* Plw = Pl[wave];

    const int ks = (i0 >= 1024) ? (i0 - 1024) : 0;
    const int nsteps = (i0 + 64 - ks) >> 6;

    auto stage = [&](int tt, int bsel) {
        const int k0s = ks + tt * 64;
        bf16* kd = Ks + bsel * 8192;
        bf16* vd = Vs + bsel * 8192;
        #pragma unroll
        for (int p = 0; p < 4; ++p) {
            int u = p * 256 + tid;
            int kk = u >> 4, sc = u & 15;
            ldg_lds16(K + (size_t)(k0s + kk) * 512 + kvh * 128 + (sc ^ (kk & 15)) * 8,
                      kd + u * 8);
        }
        #pragma unroll
        for (int p = 0; p < 4; ++p) {
            int u = p * 256 + tid;
            int d = u >> 3, sc = u & 7;
            ldg_lds16(Vt + (size_t)(kvh * 128 + d) * 4096 + k0s + (sc ^ (d & 7)) * 8,
                      vd + u * 8);
        }
    };

    // Q + cos/sin table loads first (oldest vmem ops); staging issues after,
    // so the RoPE math's data wait leaves the 16 staging loads in flight.
    bf16x8 qr_[4];
    float2 csv[16];
    {
        const bf16* qp = Q + (size_t)(q0 + l16) * 2048 + h * 128 + quad * 8;
        #pragma unroll
        for (int c = 0; c < 4; ++c)
            qr_[c] = *reinterpret_cast<const bf16x8*>(qp + c * 32);
        const float2* csp = CS + (size_t)(q0 + l16) * 64 + quad * 8;
        #pragma unroll
        for (int c = 0; c < 2; ++c)
            #pragma unroll
            for (int i = 0; i < 8; ++i)
                csv[c * 8 + i] = csp[c * 32 + i];
    }

    // prologue: stage tiles 0 and 1 (tile-1 rows always < 4096 -> in-bounds
    // even when nsteps==1; data simply unused then).
    stage(0, 0);
    stage(1, 1);

    // fused Q-RoPE via table (32 FMA, no transcendentals)
    bf16x8 qf[4];
    #pragma unroll
    for (int c = 0; c < 2; ++c) {
        #pragma unroll
        for (int i = 0; i < 8; ++i) {
            float cs_ = csv[c * 8 + i].x, sn = csv[c * 8 + i].y;
            float a = (float)qr_[c][i], b = (float)qr_[c + 2][i];
            qf[c][i]     = (bf16)(a * cs_ - b * sn);
            qf[c + 2][i] = (bf16)(b * cs_ + a * sn);
        }
    }

    f32x4 o[8] = {};
    float lsum[4] = {0.f, 0.f, 0.f, 0.f};

    asm volatile("s_waitcnt vmcnt(8)" ::: "memory");   // tile 0 landed
    __builtin_amdgcn_sched_barrier(0);
    __builtin_amdgcn_s_barrier();
    __builtin_amdgcn_sched_barrier(0);

    for (int t = 0; t < nsteps; ++t) {
        const int b  = t & 1;
        const int k0 = ks + t * 64;
        const bf16* Kb = Ks + b * 8192;
        const bf16* Vb = Vs + b * 8192;

        // S = Q K^T, four 16-key tiles (B-frags from swizzled Ks)
        f32x4 s[4];
        __builtin_amdgcn_s_setprio(1);
        #pragma unroll
        for (int kh = 0; kh < 4; ++kh) {
            const int kk = kh * 16 + l16;
            f32x4 sv = {};
            #pragma unroll
            for (int c = 0; c < 4; ++c) {
                bf16x8 kf = *reinterpret_cast<const bf16x8*>(
                    &Kb[kk * 128 + (((c * 4 + quad) ^ (kk & 15)) * 8)]);
                sv = __builtin_amdgcn_mfma_f32_16x16x32_bf16(qf[c], kf, sv, 0, 0, 0);
            }
            s[kh] = sv;
        }
        __builtin_amdgcn_s_setprio(0);

        // P = exp(mask(S*scale)), fixed max 0; packed swizzled Pl write.
        // Wave-uniform fast path: interior steps need no masking at all.
        const bool full = (k0 + 63 <= q0) && (q0 + 15 - k0 < 1024);
        if (full) {
            #pragma unroll
            for (int kh = 0; kh < 4; ++kh) {
                #pragma unroll
                for (int r = 0; r < 4; ++r) {
                    float pv = __expf(s[kh][r] * scale);
                    lsum[r] += pv;
                    const int row = quad * 4 + r;
                    const int idx = row * 64 +
                        ((((kh * 2 + (l16 >> 3)) ^ (row & 7)) << 3) | (l16 & 7));
                    Plw[idx] = (bf16)pv;
                }
            }
        } else {
            #pragma unroll
            for (int kh = 0; kh < 4; ++kh) {
                const int key = k0 + kh * 16 + l16;
                #pragma unroll
                for (int r = 0; r < 4; ++r) {
                    const int qrow = q0 + quad * 4 + r;
                    bool ok = (unsigned)(qrow - key) < 1024u;   // causal & window
                    float pv = ok ? __expf(s[kh][r] * scale) : 0.f;
                    lsum[r] += pv;
                    const int row = quad * 4 + r;
                    const int idx = row * 64 +
                        ((((kh * 2 + (l16 >> 3)) ^ (row & 7)) << 3) | (l16 & 7));
                    Plw[idx] = (bf16)pv;
                }
            }
        }

        // PV: P (A-frags, packed swizzled Pl) x V (B-frags, swizzled Vs)
        bf16x8 pf0 = *reinterpret_cast<const bf16x8*>(
            &Plw[l16 * 64 + ((quad ^ (l16 & 7)) << 3)]);
        bf16x8 pf1 = *reinterpret_cast<const bf16x8*>(
            &Plw[l16 * 64 + (((4 + quad) ^ (l16 & 7)) << 3)]);
        __builtin_amdgcn_s_setprio(1);
        #pragma unroll
        for (int n = 0; n < 8; ++n) {
            const int d = n * 16 + l16;
            bf16x8 v0 = *reinterpret_cast<const bf16x8*>(
                &Vb[d * 64 + (((quad) ^ (d & 7)) * 8)]);
            bf16x8 v1 = *reinterpret_cast<const bf16x8*>(
                &Vb[d * 64 + (((4 + quad) ^ (d & 7)) * 8)]);
            o[n] = __builtin_amdgcn_mfma_f32_16x16x32_bf16(pf0, v0, o[n], 0, 0, 0);
            o[n] = __builtin_amdgcn_mfma_f32_16x16x32_bf16(pf1, v1, o[n], 0, 0, 0);
        }
        __builtin_amdgcn_s_setprio(0);

        // ---- pipeline boundary: all reads of buf b done -> restage it
        asm volatile("s_waitcnt lgkmcnt(0)" ::: "memory");
        __builtin_amdgcn_sched_barrier(0);
        __builtin_amdgcn_s_barrier();
        __builtin_amdgcn_sched_barrier(0);

        if (t + 2 < nsteps) {
            stage(t + 2, b);
            asm volatile("s_waitcnt vmcnt(8)" ::: "memory");  // tile t+1 landed
        } else {
            asm volatile("s_waitcnt vmcnt(0)" ::: "memory");  // drain tail
        }
        __builtin_amdgcn_sched_barrier(0);
        __builtin_amdgcn_s_barrier();
        __builtin_amdgcn_sched_barrier(0);
    }

    // final: reduce l over the 16 lanes of each row (once), normalize, store
    #pragma unroll
    for (int r = 0; r < 4; ++r) {
        #pragma unroll
        for (int off = 1; off < 16; off <<= 1)
            lsum[r] += __shfl_xor(lsum[r], off, 64);
    }
    #pragma unroll
    for (int r = 0; r < 4; ++r) {
        int row = q0 + quad * 4 + r;
        float inv = (lsum[r] > 0.f) ? 1.f / lsum[r] : 0.f;
        #pragma unroll
        for (int n = 0; n < 8; ++n)
            Y[(size_t)row * 2048 + h * 128 + n * 16 + l16] = (bf16)(o[n][r] * inv);
    }
}

// ---------------------------------------------------------------------------
extern "C" void kernel_launch(void* const* d_in, const int* in_sizes, int n_in,
                              void* d_out, int out_size, void* d_ws, size_t ws_size,
                              hipStream_t stream)
{
    const float* x  = (const float*)d_in[0];
    const float* Wq = (const float*)d_in[1];
    const float* Wk = (const float*)d_in[2];
    const float* Wv = (const float*)d_in[3];
    const float* Wo = (const float*)d_in[4];
    float* out = (float*)d_out;

    const int T = 4096, DIM = 2048;

    // d_out (32MB fp32) hosts bf16 intermediates, all dead before final GEMM:
    //   [0,16M) Qb [T,2048] | [16M,20M) Kb [T,512] | [20M,24M) Vt [512][T]
    //   [24M,26M) CS table [4096][64] float2 (dead before gemm_out)
    char* po = (char*)d_out;
    bf16* Qb  = (bf16*)(po);
    bf16* Kb  = (bf16*)(po + (16u << 20));
    bf16* Vtb = (bf16*)(po + (20u << 20));
    float2* CS = (float2*)(po + (24u << 20));

    // ws (peak 28MB): [0,16M) xb -> later Yb ; [16M,28M) Wqkv^T -> later Wo^T
    char* ws = (char*)d_ws;
    bf16* xb    = (bf16*)(ws);
    bf16* Wqkvt = (bf16*)(ws + (16u << 20));
    bf16* Yb    = (bf16*)(ws);                 // reuses xb (dead after QKV GEMM)
    bf16* Wot   = (bf16*)(ws + (16u << 20));   // reuses Wqkv^T (dead after QKV GEMM)

    // 1. fused pre-pass: CS table + x->bf16 + Wq|Wk|Wv transpose-convert
    fused_pre<<<dim3(11264), 256, 0, stream>>>(x, Wq, Wk, Wv, xb, Wqkvt, CS);

    // 2. fused QKV GEMM (256x192 tiles -> 256 blocks, full CU fill)
    gemm256_qkv<<<dim3(3072 / 192, T / 256), 512, 0, stream>>>(
        xb, Wqkvt, Qb, Kb, Vtb, DIM);

    // 3. fused mid-pass: Wo^T (freed region) + K-RoPE via CS table
    fused_mid<<<dim3(8192), 256, 0, stream>>>(Wo, Wot, CS, Kb);

    // 4. attention (v11, unchanged)
    attn_v11<<<dim3(T / 64, 16), 256, 0, stream>>>(Qb, Kb, Vtb, Yb, CS);

    // 5. output projection (256x128 deep-pipelined): -> out (fp32)
    gemm_out<<<dim3(2048 / 128, T / 256), 512, 0, stream>>>(
        Yb, Wot, out, DIM);
}

// Round 10
// 270.395 us; speedup vs baseline: 1.0698x; 1.0055x over previous
//
#include <hip/hip_runtime.h>
#include <math.h>

typedef __bf16 bf16;
typedef __bf16 bf16x8 __attribute__((ext_vector_type(8)));
typedef __bf16 bf16x4 __attribute__((ext_vector_type(4)));
typedef float f32x4 __attribute__((ext_vector_type(4)));

// ---------------------------------------------------------------------------
// async global->LDS 16B (direct-to-shared DMA). LDS dest must be
// wave-uniform base + lane*16 — all staging maps below guarantee that.
// ---------------------------------------------------------------------------
__device__ __forceinline__ void ldg_lds16(const bf16* g, bf16* l) {
#if __has_builtin(__builtin_amdgcn_global_load_lds)
    __builtin_amdgcn_global_load_lds(
        (const __attribute__((address_space(1))) void*)g,
        (__attribute__((address_space(3))) void*)l, 16, 0, 0);
#else
    *(bf16x8*)l = *(const bf16x8*)g;
#endif
}

// ---------------------------------------------------------------------------
// transpose64: one 64x64 tile of W[K][Ncols] fp32 -> Wt[n][k] bf16,
// fully vectorized: float4 loads (16B/lane), bf16x8 stores (16B/lane).
// LDS fp32 t[64][65] (+1 pad -> the 8-row k-gather is 2-way = free).
// 256 threads.
// ---------------------------------------------------------------------------
__device__ __forceinline__ void transpose64(
    const float* __restrict__ W, bf16* __restrict__ Wt,
    int Ncols, int nbase, int n0, int k0, float (*t)[65], int tid)
{
    #pragma unroll
    for (int p = 0; p < 4; ++p) {
        int u = p * 256 + tid;
        int row = u >> 4, c4 = u & 15;
        f32x4 v = *reinterpret_cast<const f32x4*>(
            &W[(size_t)(k0 + row) * Ncols + n0 + c4 * 4]);
        t[row][c4 * 4 + 0] = v[0];
        t[row][c4 * 4 + 1] = v[1];
        t[row][c4 * 4 + 2] = v[2];
        t[row][c4 * 4 + 3] = v[3];
    }
    __syncthreads();
    #pragma unroll
    for (int p = 0; p < 2; ++p) {
        int u = p * 256 + tid;
        int n = u >> 3, c8 = u & 7;
        bf16x8 o;
        #pragma unroll
        for (int j = 0; j < 8; ++j)
            o[j] = (bf16)t[c8 * 8 + j][n];
        *reinterpret_cast<bf16x8*>(
            &Wt[(size_t)(nbase + n0 + n) * 2048 + k0 + c8 * 8]) = o;
    }
}

// ---------------------------------------------------------------------------
// fused_pre: rope_cs [0,1024) + cvt_x [1024,5120) + vectorized Wq|Wk|Wv
// transpose [5120,6656). All parts independent; branch block-uniform.
// ---------------------------------------------------------------------------
__global__ void fused_pre(const float* __restrict__ X,
                          const float* __restrict__ Wq,
                          const float* __restrict__ Wk,
                          const float* __restrict__ Wv,
                          bf16* __restrict__ Xb,
                          bf16* __restrict__ Wt,
                          float2* __restrict__ CS)
{
    __shared__ float t[64][65];
    const int tid = threadIdx.x;
    int blk = blockIdx.x;

    if (blk < 1024) {
        // ---- rope_cs: CS[t][j], t<4096, j<64 (2MB, L2/L3-resident)
        int idx = blk * 256 + tid;
        int j = idx & 63;
        int tt = idx >> 6;
        const float NEG_LN1E4_64 = -0.14391155806323211f;  // -ln(10000)/64
        float inv_freq = expf(NEG_LN1E4_64 * (float)j);
        float ang = (float)tt * inv_freq;
        CS[idx] = make_float2(cosf(ang), sinf(ang));
        return;
    }
    blk -= 1024;
    if (blk < 4096) {
        // ---- cvt_x: fp32 -> bf16, 8 elems/thread (total8 = 1048576)
        int idx = blk * 256 + tid;
        const float* p = X + (size_t)idx * 8;
        f32x4 a = *reinterpret_cast<const f32x4*>(p);
        f32x4 b = *reinterpret_cast<const f32x4*>(p + 4);
        bf16x8 r;
        r[0] = (bf16)a[0]; r[1] = (bf16)a[1]; r[2] = (bf16)a[2]; r[3] = (bf16)a[3];
        r[4] = (bf16)b[0]; r[5] = (bf16)b[1]; r[6] = (bf16)b[2]; r[7] = (bf16)b[3];
        *reinterpret_cast<bf16x8*>(Xb + (size_t)idx * 8) = r;
        return;
    }
    blk -= 4096;
    // ---- Wq|Wk|Wv transpose-convert, 64x64 vectorized tiles.
    // Wq: 32x32=1024 tiles, Wk: 8x32=256, Wv: 256.
    const float* W; int Ncols, nbase, nx;
    if (blk < 1024)      { W = Wq; Ncols = 2048; nbase = 0;    nx = 32; }
    else if (blk < 1280) { blk -= 1024; W = Wk; Ncols = 512; nbase = 2048; nx = 8; }
    else                 { blk -= 1280; W = Wv; Ncols = 512; nbase = 2560; nx = 8; }
    const int n0 = (blk % nx) * 64, k0 = (blk / nx) * 64;
    transpose64(W, Wt, Ncols, nbase, n0, k0, t, tid);
}

// ---------------------------------------------------------------------------
// fused_mid: vectorized Wo transpose [0,1024) + rope_k [1024,5120).
// Both depend only on gemm256_qkv.
// ---------------------------------------------------------------------------
__global__ void fused_mid(const float* __restrict__ Wo,
                          bf16* __restrict__ Wot,
                          const float2* __restrict__ CS,
                          bf16* __restrict__ Kb)
{
    __shared__ float t[64][65];
    const int tid = threadIdx.x;
    int blk = blockIdx.x;

    if (blk < 1024) {
        // ---- Wo [2048][2048] fp32 -> Wot bf16 (transposed), 64x64 tiles
        const int n0 = (blk & 31) * 64, k0 = (blk >> 5) * 64;
        transpose64(Wo, Wot, 2048, 0, n0, k0, t, tid);
        return;
    }
    blk -= 1024;
    // ---- rope_k via CS table (total = 1048576 threads)
    int idx = blk * 256 + tid;
    int j  = idx & 63;
    int th = idx >> 6;
    int tt = th >> 2;

    bf16* p = Kb + (size_t)th * 128;
    float2 cs = CS[tt * 64 + j];
    float q0 = (float)p[j], q1 = (float)p[j + 64];
    p[j]      = (bf16)(q0 * cs.x - q1 * cs.y);
    p[j + 64] = (bf16)(q1 * cs.x + q0 * cs.y);
}

// ---------------------------------------------------------------------------
// gemm256_qkv: 256Mx192N tile, BK=64, 8 waves (2Mx4N, 128x48 each), grid
// 256 blocks = 1/CU. Counted-vmcnt + T2 source-swizzle + setprio.
// (round-7 structure, unchanged)
// ---------------------------------------------------------------------------
__global__ __launch_bounds__(512, 2) void gemm256_qkv(
    const bf16* __restrict__ A, const bf16* __restrict__ Bt,
    bf16* __restrict__ Qo, bf16* __restrict__ Ko, bf16* __restrict__ Vt,
    int K)
{
    __shared__ __align__(16) bf16 smem[2 * 28672];   // 112 KB: [buf][A|B]

    const int tid  = threadIdx.x;
    const int lane = tid & 63;
    const int wave = tid >> 6;
    const int quad = lane >> 4;
    const int l16  = lane & 15;
    const int wm   = wave >> 2;          // 0..1  (M half, 128 rows)
    const int wn   = wave & 3;           // 0..3  (48 cols each)

    const int m0 = blockIdx.y * 256;
    const int n0 = blockIdx.x * 192;

    int offA[4], offB[3];
    #pragma unroll
    for (int p = 0; p < 4; ++p) {
        int u = p * 512 + tid;
        int row = u >> 3;
        int kc8 = (u & 7) ^ (row & 7);
        offA[p] = (m0 + row) * K + kc8 * 8;
    }
    #pragma unroll
    for (int p = 0; p < 3; ++p) {
        int u = p * 512 + tid;
        int row = u >> 3;                // 0..191
        int kc8 = (u & 7) ^ (row & 7);
        offB[p] = (n0 + row) * K + kc8 * 8;
    }
    const int dstoff = tid * 8;

    const int xv = (l16 & 7) << 4;
    const int c0 = ((quad * 16) ^ xv) >> 1;
    const int c1 = ((64 + quad * 16) ^ xv) >> 1;
    const int rA = (wm * 128 + l16) * 64;
    const int rB = (wn * 48 + l16) * 64;

    f32x4 acc[8][3] = {};
    const int NT = K >> 6;               // 32

    auto stage = [&](int tt, int bsel) {
        bf16* as = smem + bsel * 28672;
        bf16* bs = as + 16384;
        const int koff = tt * 64;
        #pragma unroll
        for (int p = 0; p < 4; ++p)
            ldg_lds16(A + offA[p] + koff, as + p * 4096 + dstoff);
        #pragma unroll
        for (int p = 0; p < 3; ++p)
            ldg_lds16(Bt + offB[p] + koff, bs + p * 4096 + dstoff);
    };

    stage(0, 0);
    stage(1, 1);
    asm volatile("s_waitcnt vmcnt(7)" ::: "memory");
    __builtin_amdgcn_sched_barrier(0);
    __builtin_amdgcn_s_barrier();
    __builtin_amdgcn_sched_barrier(0);

    for (int t = 0; t < NT; ++t) {
        const bf16* As = smem + (t & 1) * 28672;
        const bf16* Bs = As + 16384;

        bf16x8 a0[8], b0[3];
        #pragma unroll
        for (int i = 0; i < 8; ++i)
            a0[i] = *(const bf16x8*)(As + rA + i * 1024 + c0);
        #pragma unroll
        for (int i = 0; i < 3; ++i)
            b0[i] = *(const bf16x8*)(Bs + rB + i * 1024 + c0);

        #pragma unroll
        for (int mi = 0; mi < 8; ++mi)
            #pragma unroll
            for (int ni = 0; ni < 3; ++ni)
                acc[mi][ni] = __builtin_amdgcn_mfma_f32_16x16x32_bf16(
                    a0[mi], b0[ni], acc[mi][ni], 0, 0, 0);

        bf16x8 a1[8], b1[3];
        #pragma unroll
        for (int i = 0; i < 8; ++i)
            a1[i] = *(const bf16x8*)(As + rA + i * 1024 + c1);
        #pragma unroll
        for (int i = 0; i < 3; ++i)
            b1[i] = *(const bf16x8*)(Bs + rB + i * 1024 + c1);

        asm volatile("s_waitcnt lgkmcnt(0)" ::: "memory");
        __builtin_amdgcn_sched_barrier(0);
        __builtin_amdgcn_s_barrier();
        __builtin_amdgcn_sched_barrier(0);

        if (t + 2 < NT) stage(t + 2, t & 1);

        __builtin_amdgcn_s_setprio(1);
        #pragma unroll
        for (int mi = 0; mi < 8; ++mi)
            #pragma unroll
            for (int ni = 0; ni < 3; ++ni)
                acc[mi][ni] = __builtin_amdgcn_mfma_f32_16x16x32_bf16(
                    a1[mi], b1[ni], acc[mi][ni], 0, 0, 0);
        __builtin_amdgcn_s_setprio(0);

        if (t + 2 < NT) {
            asm volatile("s_waitcnt vmcnt(7)" ::: "memory");  // tile t+1 landed
            __builtin_amdgcn_sched_barrier(0);
            __builtin_amdgcn_s_barrier();
            __builtin_amdgcn_sched_barrier(0);
        } else if (t == NT - 2) {
            asm volatile("s_waitcnt vmcnt(0)" ::: "memory");
            __builtin_amdgcn_sched_barrier(0);
            __builtin_amdgcn_s_barrier();
            __builtin_amdgcn_sched_barrier(0);
        }
    }

    #pragma unroll
    for (int mi = 0; mi < 8; ++mi) {
        #pragma unroll
        for (int ni = 0; ni < 3; ++ni) {
            const int row = m0 + wm * 128 + mi * 16 + quad * 4;
            const int col = n0 + wn * 48 + ni * 16 + l16;
            const int cb  = n0 + wn * 48 + ni * 16;    // wave-uniform base
            if (cb < 2048) {            // Q region
                #pragma unroll
                for (int r = 0; r < 4; ++r)
                    Qo[(size_t)(row + r) * 2048 + col] = (bf16)acc[mi][ni][r];
            } else if (cb < 2560) {     // K region
                #pragma unroll
                for (int r = 0; r < 4; ++r)
                    Ko[(size_t)(row + r) * 512 + (col - 2048)] = (bf16)acc[mi][ni][r];
            } else {                    // V region -> transposed Vt[d][t]
                bf16x4 v;
                #pragma unroll
                for (int r = 0; r < 4; ++r) v[r] = (bf16)acc[mi][ni][r];
                *reinterpret_cast<bf16x4*>(&Vt[(size_t)(col - 2560) * 4096 + row]) = v;
            }
        }
    }
}

// ---------------------------------------------------------------------------
// gemm_out: C[4096,2048] = A @ Bt^T, fp32 C. 256Mx128N, BK=64, 8 waves,
// counted-vmcnt pipeline. (proven round 4, unchanged)
// ---------------------------------------------------------------------------
__global__ __launch_bounds__(512, 2) void gemm_out(
    const bf16* __restrict__ A, const bf16* __restrict__ Bt,
    float* __restrict__ C, int K)
{
    __shared__ __align__(16) bf16 smem[2 * 24576];   // 96 KB: [buf][A|B]

    const int tid  = threadIdx.x;
    const int lane = tid & 63;
    const int wave = tid >> 6;
    const int quad = lane >> 4;
    const int l16  = lane & 15;
    const int wm   = wave >> 1;
    const int wn   = wave & 1;

    const int m0 = blockIdx.y * 256;
    const int n0 = blockIdx.x * 128;

    int offA[4], offB[2];
    #pragma unroll
    for (int p = 0; p < 4; ++p) {
        int u = p * 512 + tid;
        int row = u >> 3;
        int kc8 = (u & 7) ^ (row & 7);
        offA[p] = (m0 + row) * K + kc8 * 8;
    }
    #pragma unroll
    for (int p = 0; p < 2; ++p) {
        int u = p * 512 + tid;
        int row = u >> 3;
        int kc8 = (u & 7) ^ (row & 7);
        offB[p] = (n0 + row) * K + kc8 * 8;
    }
    const int dstoff = tid * 8;

    const int xv = (l16 & 7) << 4;
    const int c0 = ((quad * 16) ^ xv) >> 1;
    const int c1 = ((64 + quad * 16) ^ xv) >> 1;
    const int rA = (wm * 64 + l16) * 64;
    const int rB = (wn * 64 + l16) * 64;

    f32x4 acc[4][4] = {};
    const int NT = K >> 6;

    auto stage = [&](int tt, int bsel) {
        bf16* as = smem + bsel * 24576;
        bf16* bs = as + 16384;
        const int koff = tt * 64;
        #pragma unroll
        for (int p = 0; p < 4; ++p)
            ldg_lds16(A + offA[p] + koff, as + p * 4096 + dstoff);
        #pragma unroll
        for (int p = 0; p < 2; ++p)
            ldg_lds16(Bt + offB[p] + koff, bs + p * 4096 + dstoff);
    };

    stage(0, 0);
    stage(1, 1);
    asm volatile("s_waitcnt vmcnt(6)" ::: "memory");
    __builtin_amdgcn_sched_barrier(0);
    __builtin_amdgcn_s_barrier();
    __builtin_amdgcn_sched_barrier(0);

    for (int t = 0; t < NT; ++t) {
        const bf16* As = smem + (t & 1) * 24576;
        const bf16* Bs = As + 16384;

        bf16x8 a0[4], b0[4];
        #pragma unroll
        for (int i = 0; i < 4; ++i)
            a0[i] = *(const bf16x8*)(As + rA + i * 1024 + c0);
        #pragma unroll
        for (int i = 0; i < 4; ++i)
            b0[i] = *(const bf16x8*)(Bs + rB + i * 1024 + c0);

        #pragma unroll
        for (int mi = 0; mi < 4; ++mi)
            #pragma unroll
            for (int ni = 0; ni < 4; ++ni)
                acc[mi][ni] = __builtin_amdgcn_mfma_f32_16x16x32_bf16(
                    a0[mi], b0[ni], acc[mi][ni], 0, 0, 0);

        bf16x8 a1[4], b1[4];
        #pragma unroll
        for (int i = 0; i < 4; ++i)
            a1[i] = *(const bf16x8*)(As + rA + i * 1024 + c1);
        #pragma unroll
        for (int i = 0; i < 4; ++i)
            b1[i] = *(const bf16x8*)(Bs + rB + i * 1024 + c1);

        asm volatile("s_waitcnt lgkmcnt(0)" ::: "memory");
        __builtin_amdgcn_sched_barrier(0);
        __builtin_amdgcn_s_barrier();
        __builtin_amdgcn_sched_barrier(0);

        if (t + 2 < NT) stage(t + 2, t & 1);

        __builtin_amdgcn_s_setprio(1);
        #pragma unroll
        for (int mi = 0; mi < 4; ++mi)
            #pragma unroll
            for (int ni = 0; ni < 4; ++ni)
                acc[mi][ni] = __builtin_amdgcn_mfma_f32_16x16x32_bf16(
                    a1[mi], b1[ni], acc[mi][ni], 0, 0, 0);
        __builtin_amdgcn_s_setprio(0);

        if (t + 2 < NT) {
            asm volatile("s_waitcnt vmcnt(6)" ::: "memory");
            __builtin_amdgcn_sched_barrier(0);
            __builtin_amdgcn_s_barrier();
            __builtin_amdgcn_sched_barrier(0);
        } else if (t == NT - 2) {
            asm volatile("s_waitcnt vmcnt(0)" ::: "memory");
            __builtin_amdgcn_sched_barrier(0);
            __builtin_amdgcn_s_barrier();
            __builtin_amdgcn_sched_barrier(0);
        }
    }

    #pragma unroll
    for (int mi = 0; mi < 4; ++mi) {
        #pragma unroll
        for (int ni = 0; ni < 4; ++ni) {
            const int row = m0 + wm * 64 + mi * 16 + quad * 4;
            const int col = n0 + wn * 64 + ni * 16 + l16;
            #pragma unroll
            for (int r = 0; r < 4; ++r)
                C[(size_t)(row + r) * 2048 + col] = acc[mi][ni][r];
        }
    }
}

// ---------------------------------------------------------------------------
// attn_v11: flash attention, sliding window 1024, causal, GQA.
// (round-8 structure, measured 72.9us, unchanged)
// ---------------------------------------------------------------------------
__global__ __launch_bounds__(256) void attn_v11(
    const bf16* __restrict__ Q, const bf16* __restrict__ K,
    const bf16* __restrict__ Vt, bf16* __restrict__ Y,
    const float2* __restrict__ CS)
{
    const float scale = 0.08838834764831845f;  // 1/sqrt(128)

    __shared__ __align__(16) bf16 Ks[2 * 64 * 128];  // [buf][kk][128d], chunk^=(kk&15)
    __shared__ __align__(16) bf16 Vs[2 * 128 * 64];  // [buf][d][64k],   chunk^=(d&7)
    __shared__ __align__(16) bf16 Pl[4][16 * 64];    // [row][64k],      chunk^=(row&7)

    const int tid  = threadIdx.x;
    const int lane = tid & 63;
    const int wave = tid >> 6;
    const int quad = lane >> 4;
    const int l16  = lane & 15;

    const int i0  = (gridDim.x - 1 - blockIdx.x) * 64;   // long blocks first
    const int h   = blockIdx.y;
    const int kvh = h >> 2;
    const int q0  = i0 + wave * 16;
    bf16* Plw = Pl[wave];

    const int ks = (i0 >= 1024) ? (i0 - 1024) : 0;
    const int nsteps = (i0 + 64 - ks) >> 6;

    auto stage = [&](int tt, int bsel) {
        const int k0s = ks + tt * 64;
        bf16* kd = Ks + bsel * 8192;
        bf16* vd = Vs + bsel * 8192;
        #pragma unroll
        for (int p = 0; p < 4; ++p) {
            int u = p * 256 + tid;
            int kk = u >> 4, sc = u & 15;
            ldg_lds16(K + (size_t)(k0s + kk) * 512 + kvh * 128 + (sc ^ (kk & 15)) * 8,
                      kd + u * 8);
        }
        #pragma unroll
        for (int p = 0; p < 4; ++p) {
            int u = p * 256 + tid;
            int d = u >> 3, sc = u & 7;
            ldg_lds16(Vt + (size_t)(kvh * 128 + d) * 4096 + k0s + (sc ^ (d & 7)) * 8,
                      vd + u * 8);
        }
    };

    // Q + cos/sin table loads first (oldest vmem ops); staging issues after,
    // so the RoPE math's data wait leaves the 16 staging loads in flight.
    bf16x8 qr_[4];
    float2 csv[16];
    {
        const bf16* qp = Q + (size_t)(q0 + l16) * 2048 + h * 128 + quad * 8;
        #pragma unroll
        for (int c = 0; c < 4; ++c)
            qr_[c] = *reinterpret_cast<const bf16x8*>(qp + c * 32);
        const float2* csp = CS + (size_t)(q0 + l16) * 64 + quad * 8;
        #pragma unroll
        for (int c = 0; c < 2; ++c)
            #pragma unroll
            for (int i = 0; i < 8; ++i)
                csv[c * 8 + i] = csp[c * 32 + i];
    }

    // prologue: stage tiles 0 and 1 (tile-1 rows always < 4096 -> in-bounds
    // even when nsteps==1; data simply unused then).
    stage(0, 0);
    stage(1, 1);

    // fused Q-RoPE via table (32 FMA, no transcendentals)
    bf16x8 qf[4];
    #pragma unroll
    for (int c = 0; c < 2; ++c) {
        #pragma unroll
        for (int i = 0; i < 8; ++i) {
            float cs_ = csv[c * 8 + i].x, sn = csv[c * 8 + i].y;
            float a = (float)qr_[c][i], b = (float)qr_[c + 2][i];
            qf[c][i]     = (bf16)(a * cs_ - b * sn);
            qf[c + 2][i] = (bf16)(b * cs_ + a * sn);
        }
    }

    f32x4 o[8] = {};
    float lsum[4] = {0.f, 0.f, 0.f, 0.f};

    asm volatile("s_waitcnt vmcnt(8)" ::: "memory");   // tile 0 landed
    __builtin_amdgcn_sched_barrier(0);
    __builtin_amdgcn_s_barrier();
    __builtin_amdgcn_sched_barrier(0);

    for (int t = 0; t < nsteps; ++t) {
        const int b  = t & 1;
        const int k0 = ks + t * 64;
        const bf16* Kb = Ks + b * 8192;
        const bf16* Vb = Vs + b * 8192;

        // S = Q K^T, four 16-key tiles (B-frags from swizzled Ks)
        f32x4 s[4];
        __builtin_amdgcn_s_setprio(1);
        #pragma unroll
        for (int kh = 0; kh < 4; ++kh) {
            const int kk = kh * 16 + l16;
            f32x4 sv = {};
            #pragma unroll
            for (int c = 0; c < 4; ++c) {
                bf16x8 kf = *reinterpret_cast<const bf16x8*>(
                    &Kb[kk * 128 + (((c * 4 + quad) ^ (kk & 15)) * 8)]);
                sv = __builtin_amdgcn_mfma_f32_16x16x32_bf16(qf[c], kf, sv, 0, 0, 0);
            }
            s[kh] = sv;
        }
        __builtin_amdgcn_s_setprio(0);

        // P = exp(mask(S*scale)), fixed max 0; packed swizzled Pl write.
        // Wave-uniform fast path: interior steps need no masking at all.
        const bool full = (k0 + 63 <= q0) && (q0 + 15 - k0 < 1024);
        if (full) {
            #pragma unroll
            for (int kh = 0; kh < 4; ++kh) {
                #pragma unroll
                for (int r = 0; r < 4; ++r) {
                    float pv = __expf(s[kh][r] * scale);
                    lsum[r] += pv;
                    const int row = quad * 4 + r;
                    const int idx = row * 64 +
                        ((((kh * 2 + (l16 >> 3)) ^ (row & 7)) << 3) | (l16 & 7));
                    Plw[idx] = (bf16)pv;
                }
            }
        } else {
            #pragma unroll
            for (int kh = 0; kh < 4; ++kh) {
                const int key = k0 + kh * 16 + l16;
                #pragma unroll
                for (int r = 0; r < 4; ++r) {
                    const int qrow = q0 + quad * 4 + r;
                    bool ok = (unsigned)(qrow - key) < 1024u;   // causal & window
                    float pv = ok ? __expf(s[kh][r] * scale) : 0.f;
                    lsum[r] += pv;
                    const int row = quad * 4 + r;
                    const int idx = row * 64 +
                        ((((kh * 2 + (l16 >> 3)) ^ (row & 7)) << 3) | (l16 & 7));
                    Plw[idx] = (bf16)pv;
                }
            }
        }

        // PV: P (A-frags, packed swizzled Pl) x V (B-frags, swizzled Vs)
        bf16x8 pf0 = *reinterpret_cast<const bf16x8*>(
            &Plw[l16 * 64 + ((quad ^ (l16 & 7)) << 3)]);
        bf16x8 pf1 = *reinterpret_cast<const bf16x8*>(
            &Plw[l16 * 64 + (((4 + quad) ^ (l16 & 7)) << 3)]);
        __builtin_amdgcn_s_setprio(1);
        #pragma unroll
        for (int n = 0; n < 8; ++n) {
            const int d = n * 16 + l16;
            bf16x8 v0 = *reinterpret_cast<const bf16x8*>(
                &Vb[d * 64 + (((quad) ^ (d & 7)) * 8)]);
            bf16x8 v1 = *reinterpret_cast<const bf16x8*>(
                &Vb[d * 64 + (((4 + quad) ^ (d & 7)) * 8)]);
            o[n] = __builtin_amdgcn_mfma_f32_16x16x32_bf16(pf0, v0, o[n], 0, 0, 0);
            o[n] = __builtin_amdgcn_mfma_f32_16x16x32_bf16(pf1, v1, o[n], 0, 0, 0);
        }
        __builtin_amdgcn_s_setprio(0);

        // ---- pipeline boundary: all reads of buf b done -> restage it
        asm volatile("s_waitcnt lgkmcnt(0)" ::: "memory");
        __builtin_amdgcn_sched_barrier(0);
        __builtin_amdgcn_s_barrier();
        __builtin_amdgcn_sched_barrier(0);

        if (t + 2 < nsteps) {
            stage(t + 2, b);
            asm volatile("s_waitcnt vmcnt(8)" ::: "memory");  // tile t+1 landed
        } else {
            asm volatile("s_waitcnt vmcnt(0)" ::: "memory");  // drain tail
        }
        __builtin_amdgcn_sched_barrier(0);
        __builtin_amdgcn_s_barrier();
        __builtin_amdgcn_sched_barrier(0);
    }

    // final: reduce l over the 16 lanes of each row (once), normalize, store
    #pragma unroll
    for (int r = 0; r < 4; ++r) {
        #pragma unroll
        for (int off = 1; off < 16; off <<= 1)
            lsum[r] += __shfl_xor(lsum[r], off, 64);
    }
    #pragma unroll
    for (int r = 0; r < 4; ++r) {
        int row = q0 + quad * 4 + r;
        float inv = (lsum[r] > 0.f) ? 1.f / lsum[r] : 0.f;
        #pragma unroll
        for (int n = 0; n < 8; ++n)
            Y[(size_t)row * 2048 + h * 128 + n * 16 + l16] = (bf16)(o[n][r] * inv);
    }
}

// ---------------------------------------------------------------------------
extern "C" void kernel_launch(void* const* d_in, const int* in_sizes, int n_in,
                              void* d_out, int out_size, void* d_ws, size_t ws_size,
                              hipStream_t stream)
{
    const float* x  = (const float*)d_in[0];
    const float* Wq = (const float*)d_in[1];
    const float* Wk = (const float*)d_in[2];
    const float* Wv = (const float*)d_in[3];
    const float* Wo = (const float*)d_in[4];
    float* out = (float*)d_out;

    const int T = 4096, DIM = 2048;

    // d_out (32MB fp32) hosts bf16 intermediates, all dead before final GEMM:
    //   [0,16M) Qb [T,2048] | [16M,20M) Kb [T,512] | [20M,24M) Vt [512][T]
    //   [24M,26M) CS table [4096][64] float2 (dead before gemm_out)
    char* po = (char*)d_out;
    bf16* Qb  = (bf16*)(po);
    bf16* Kb  = (bf16*)(po + (16u << 20));
    bf16* Vtb = (bf16*)(po + (20u << 20));
    float2* CS = (float2*)(po + (24u << 20));

    // ws (peak 28MB): [0,16M) xb -> later Yb ; [16M,28M) Wqkv^T -> later Wo^T
    char* ws = (char*)d_ws;
    bf16* xb    = (bf16*)(ws);
    bf16* Wqkvt = (bf16*)(ws + (16u << 20));
    bf16* Yb    = (bf16*)(ws);                 // reuses xb (dead after QKV GEMM)
    bf16* Wot   = (bf16*)(ws + (16u << 20));   // reuses Wqkv^T (dead after QKV GEMM)

    // 1. fused pre-pass: CS table + x->bf16 + vectorized W transposes
    fused_pre<<<dim3(6656), 256, 0, stream>>>(x, Wq, Wk, Wv, xb, Wqkvt, CS);

    // 2. fused QKV GEMM (256x192 tiles -> 256 blocks, full CU fill)
    gemm256_qkv<<<dim3(3072 / 192, T / 256), 512, 0, stream>>>(
        xb, Wqkvt, Qb, Kb, Vtb, DIM);

    // 3. fused mid-pass: vectorized Wo^T (freed region) + K-RoPE via CS table
    fused_mid<<<dim3(5120), 256, 0, stream>>>(Wo, Wot, CS, Kb);

    // 4. attention (v11, unchanged)
    attn_v11<<<dim3(T / 64, 16), 256, 0, stream>>>(Qb, Kb, Vtb, Yb, CS);

    // 5. output projection (256x128 deep-pipelined): -> out (fp32)
    gemm_out<<<dim3(2048 / 128, T / 256), 512, 0, stream>>>(
        Yb, Wot, out, DIM);
}

// Round 11
// 257.831 us; speedup vs baseline: 1.1219x; 1.0487x over previous
//
#include <hip/hip_runtime.h>
#include <math.h>

typedef __bf16 bf16;
typedef __bf16 bf16x8 __attribute__((ext_vector_type(8)));
typedef __bf16 bf16x4 __attribute__((ext_vector_type(4)));
typedef float f32x4 __attribute__((ext_vector_type(4)));

// ---------------------------------------------------------------------------
// async global->LDS 16B (direct-to-shared DMA). LDS dest must be
// wave-uniform base + lane*16 — all staging maps below guarantee that.
// ---------------------------------------------------------------------------
__device__ __forceinline__ void ldg_lds16(const bf16* g, bf16* l) {
#if __has_builtin(__builtin_amdgcn_global_load_lds)
    __builtin_amdgcn_global_load_lds(
        (const __attribute__((address_space(1))) void*)g,
        (__attribute__((address_space(3))) void*)l, 16, 0, 0);
#else
    *(bf16x8*)l = *(const bf16x8*)g;
#endif
}

// ---------------------------------------------------------------------------
// transpose64: one 64x64 tile of W[K][Ncols] fp32 -> Wt[n][k] bf16,
// fully vectorized: float4 loads (16B/lane), bf16x8 stores (16B/lane).
// ---------------------------------------------------------------------------
__device__ __forceinline__ void transpose64(
    const float* __restrict__ W, bf16* __restrict__ Wt,
    int Ncols, int nbase, int n0, int k0, float (*t)[65], int tid)
{
    #pragma unroll
    for (int p = 0; p < 4; ++p) {
        int u = p * 256 + tid;
        int row = u >> 4, c4 = u & 15;
        f32x4 v = *reinterpret_cast<const f32x4*>(
            &W[(size_t)(k0 + row) * Ncols + n0 + c4 * 4]);
        t[row][c4 * 4 + 0] = v[0];
        t[row][c4 * 4 + 1] = v[1];
        t[row][c4 * 4 + 2] = v[2];
        t[row][c4 * 4 + 3] = v[3];
    }
    __syncthreads();
    #pragma unroll
    for (int p = 0; p < 2; ++p) {
        int u = p * 256 + tid;
        int n = u >> 3, c8 = u & 7;
        bf16x8 o;
        #pragma unroll
        for (int j = 0; j < 8; ++j)
            o[j] = (bf16)t[c8 * 8 + j][n];
        *reinterpret_cast<bf16x8*>(
            &Wt[(size_t)(nbase + n0 + n) * 2048 + k0 + c8 * 8]) = o;
    }
}

// ---------------------------------------------------------------------------
// fused_pre: rope_cs [0,1024) + cvt_x [1024,5120) + vectorized Wq|Wk|Wv
// transpose [5120,6656). (round-10 structure, unchanged)
// ---------------------------------------------------------------------------
__global__ void fused_pre(const float* __restrict__ X,
                          const float* __restrict__ Wq,
                          const float* __restrict__ Wk,
                          const float* __restrict__ Wv,
                          bf16* __restrict__ Xb,
                          bf16* __restrict__ Wt,
                          float2* __restrict__ CS)
{
    __shared__ float t[64][65];
    const int tid = threadIdx.x;
    int blk = blockIdx.x;

    if (blk < 1024) {
        int idx = blk * 256 + tid;
        int j = idx & 63;
        int tt = idx >> 6;
        const float NEG_LN1E4_64 = -0.14391155806323211f;  // -ln(10000)/64
        float inv_freq = expf(NEG_LN1E4_64 * (float)j);
        float ang = (float)tt * inv_freq;
        CS[idx] = make_float2(cosf(ang), sinf(ang));
        return;
    }
    blk -= 1024;
    if (blk < 4096) {
        int idx = blk * 256 + tid;
        const float* p = X + (size_t)idx * 8;
        f32x4 a = *reinterpret_cast<const f32x4*>(p);
        f32x4 b = *reinterpret_cast<const f32x4*>(p + 4);
        bf16x8 r;
        r[0] = (bf16)a[0]; r[1] = (bf16)a[1]; r[2] = (bf16)a[2]; r[3] = (bf16)a[3];
        r[4] = (bf16)b[0]; r[5] = (bf16)b[1]; r[6] = (bf16)b[2]; r[7] = (bf16)b[3];
        *reinterpret_cast<bf16x8*>(Xb + (size_t)idx * 8) = r;
        return;
    }
    blk -= 4096;
    const float* W; int Ncols, nbase, nx;
    if (blk < 1024)      { W = Wq; Ncols = 2048; nbase = 0;    nx = 32; }
    else if (blk < 1280) { blk -= 1024; W = Wk; Ncols = 512; nbase = 2048; nx = 8; }
    else                 { blk -= 1280; W = Wv; Ncols = 512; nbase = 2560; nx = 8; }
    const int n0 = (blk % nx) * 64, k0 = (blk / nx) * 64;
    transpose64(W, Wt, Ncols, nbase, n0, k0, t, tid);
}

// ---------------------------------------------------------------------------
// fused_mid: vectorized Wo transpose [0,1024) + rope_k [1024,5120).
// (round-10 structure, unchanged)
// ---------------------------------------------------------------------------
__global__ void fused_mid(const float* __restrict__ Wo,
                          bf16* __restrict__ Wot,
                          const float2* __restrict__ CS,
                          bf16* __restrict__ Kb)
{
    __shared__ float t[64][65];
    const int tid = threadIdx.x;
    int blk = blockIdx.x;

    if (blk < 1024) {
        const int n0 = (blk & 31) * 64, k0 = (blk >> 5) * 64;
        transpose64(Wo, Wot, 2048, 0, n0, k0, t, tid);
        return;
    }
    blk -= 1024;
    int idx = blk * 256 + tid;
    int j  = idx & 63;
    int th = idx >> 6;
    int tt = th >> 2;

    bf16* p = Kb + (size_t)th * 128;
    float2 cs = CS[tt * 64 + j];
    float q0 = (float)p[j], q1 = (float)p[j + 64];
    p[j]      = (bf16)(q0 * cs.x - q1 * cs.y);
    p[j + 64] = (bf16)(q1 * cs.x + q0 * cs.y);
}

// ---------------------------------------------------------------------------
// gemm256_qkv: 256Mx192N tile, BK=64, 8 waves, 256 blocks = 1/CU.
// Counted-vmcnt + T2 source-swizzle + setprio. (round-7 structure, unchanged)
// ---------------------------------------------------------------------------
__global__ __launch_bounds__(512, 2) void gemm256_qkv(
    const bf16* __restrict__ A, const bf16* __restrict__ Bt,
    bf16* __restrict__ Qo, bf16* __restrict__ Ko, bf16* __restrict__ Vt,
    int K)
{
    __shared__ __align__(16) bf16 smem[2 * 28672];   // 112 KB: [buf][A|B]

    const int tid  = threadIdx.x;
    const int lane = tid & 63;
    const int wave = tid >> 6;
    const int quad = lane >> 4;
    const int l16  = lane & 15;
    const int wm   = wave >> 2;          // 0..1  (M half, 128 rows)
    const int wn   = wave & 3;           // 0..3  (48 cols each)

    const int m0 = blockIdx.y * 256;
    const int n0 = blockIdx.x * 192;

    int offA[4], offB[3];
    #pragma unroll
    for (int p = 0; p < 4; ++p) {
        int u = p * 512 + tid;
        int row = u >> 3;
        int kc8 = (u & 7) ^ (row & 7);
        offA[p] = (m0 + row) * K + kc8 * 8;
    }
    #pragma unroll
    for (int p = 0; p < 3; ++p) {
        int u = p * 512 + tid;
        int row = u >> 3;                // 0..191
        int kc8 = (u & 7) ^ (row & 7);
        offB[p] = (n0 + row) * K + kc8 * 8;
    }
    const int dstoff = tid * 8;

    const int xv = (l16 & 7) << 4;
    const int c0 = ((quad * 16) ^ xv) >> 1;
    const int c1 = ((64 + quad * 16) ^ xv) >> 1;
    const int rA = (wm * 128 + l16) * 64;
    const int rB = (wn * 48 + l16) * 64;

    f32x4 acc[8][3] = {};
    const int NT = K >> 6;               // 32

    auto stage = [&](int tt, int bsel) {
        bf16* as = smem + bsel * 28672;
        bf16* bs = as + 16384;
        const int koff = tt * 64;
        #pragma unroll
        for (int p = 0; p < 4; ++p)
            ldg_lds16(A + offA[p] + koff, as + p * 4096 + dstoff);
        #pragma unroll
        for (int p = 0; p < 3; ++p)
            ldg_lds16(Bt + offB[p] + koff, bs + p * 4096 + dstoff);
    };

    stage(0, 0);
    stage(1, 1);
    asm volatile("s_waitcnt vmcnt(7)" ::: "memory");
    __builtin_amdgcn_sched_barrier(0);
    __builtin_amdgcn_s_barrier();
    __builtin_amdgcn_sched_barrier(0);

    for (int t = 0; t < NT; ++t) {
        const bf16* As = smem + (t & 1) * 28672;
        const bf16* Bs = As + 16384;

        bf16x8 a0[8], b0[3];
        #pragma unroll
        for (int i = 0; i < 8; ++i)
            a0[i] = *(const bf16x8*)(As + rA + i * 1024 + c0);
        #pragma unroll
        for (int i = 0; i < 3; ++i)
            b0[i] = *(const bf16x8*)(Bs + rB + i * 1024 + c0);

        #pragma unroll
        for (int mi = 0; mi < 8; ++mi)
            #pragma unroll
            for (int ni = 0; ni < 3; ++ni)
                acc[mi][ni] = __builtin_amdgcn_mfma_f32_16x16x32_bf16(
                    a0[mi], b0[ni], acc[mi][ni], 0, 0, 0);

        bf16x8 a1[8], b1[3];
        #pragma unroll
        for (int i = 0; i < 8; ++i)
            a1[i] = *(const bf16x8*)(As + rA + i * 1024 + c1);
        #pragma unroll
        for (int i = 0; i < 3; ++i)
            b1[i] = *(const bf16x8*)(Bs + rB + i * 1024 + c1);

        asm volatile("s_waitcnt lgkmcnt(0)" ::: "memory");
        __builtin_amdgcn_sched_barrier(0);
        __builtin_amdgcn_s_barrier();
        __builtin_amdgcn_sched_barrier(0);

        if (t + 2 < NT) stage(t + 2, t & 1);

        __builtin_amdgcn_s_setprio(1);
        #pragma unroll
        for (int mi = 0; mi < 8; ++mi)
            #pragma unroll
            for (int ni = 0; ni < 3; ++ni)
                acc[mi][ni] = __builtin_amdgcn_mfma_f32_16x16x32_bf16(
                    a1[mi], b1[ni], acc[mi][ni], 0, 0, 0);
        __builtin_amdgcn_s_setprio(0);

        if (t + 2 < NT) {
            asm volatile("s_waitcnt vmcnt(7)" ::: "memory");  // tile t+1 landed
            __builtin_amdgcn_sched_barrier(0);
            __builtin_amdgcn_s_barrier();
            __builtin_amdgcn_sched_barrier(0);
        } else if (t == NT - 2) {
            asm volatile("s_waitcnt vmcnt(0)" ::: "memory");
            __builtin_amdgcn_sched_barrier(0);
            __builtin_amdgcn_s_barrier();
            __builtin_amdgcn_sched_barrier(0);
        }
    }

    #pragma unroll
    for (int mi = 0; mi < 8; ++mi) {
        #pragma unroll
        for (int ni = 0; ni < 3; ++ni) {
            const int row = m0 + wm * 128 + mi * 16 + quad * 4;
            const int col = n0 + wn * 48 + ni * 16 + l16;
            const int cb  = n0 + wn * 48 + ni * 16;    // wave-uniform base
            if (cb < 2048) {            // Q region
                #pragma unroll
                for (int r = 0; r < 4; ++r)
                    Qo[(size_t)(row + r) * 2048 + col] = (bf16)acc[mi][ni][r];
            } else if (cb < 2560) {     // K region
                #pragma unroll
                for (int r = 0; r < 4; ++r)
                    Ko[(size_t)(row + r) * 512 + (col - 2048)] = (bf16)acc[mi][ni][r];
            } else {                    // V region -> transposed Vt[d][t]
                bf16x4 v;
                #pragma unroll
                for (int r = 0; r < 4; ++r) v[r] = (bf16)acc[mi][ni][r];
                *reinterpret_cast<bf16x4*>(&Vt[(size_t)(col - 2560) * 4096 + row]) = v;
            }
        }
    }
}

// ---------------------------------------------------------------------------
// gemm_out: C[4096,2048] = A @ Bt^T, fp32 C. 256Mx128N, BK=64, 8 waves,
// counted-vmcnt pipeline. (proven round 4, unchanged)
// ---------------------------------------------------------------------------
__global__ __launch_bounds__(512, 2) void gemm_out(
    const bf16* __restrict__ A, const bf16* __restrict__ Bt,
    float* __restrict__ C, int K)
{
    __shared__ __align__(16) bf16 smem[2 * 24576];   // 96 KB: [buf][A|B]

    const int tid  = threadIdx.x;
    const int lane = tid & 63;
    const int wave = tid >> 6;
    const int quad = lane >> 4;
    const int l16  = lane & 15;
    const int wm   = wave >> 1;
    const int wn   = wave & 1;

    const int m0 = blockIdx.y * 256;
    const int n0 = blockIdx.x * 128;

    int offA[4], offB[2];
    #pragma unroll
    for (int p = 0; p < 4; ++p) {
        int u = p * 512 + tid;
        int row = u >> 3;
        int kc8 = (u & 7) ^ (row & 7);
        offA[p] = (m0 + row) * K + kc8 * 8;
    }
    #pragma unroll
    for (int p = 0; p < 2; ++p) {
        int u = p * 512 + tid;
        int row = u >> 3;
        int kc8 = (u & 7) ^ (row & 7);
        offB[p] = (n0 + row) * K + kc8 * 8;
    }
    const int dstoff = tid * 8;

    const int xv = (l16 & 7) << 4;
    const int c0 = ((quad * 16) ^ xv) >> 1;
    const int c1 = ((64 + quad * 16) ^ xv) >> 1;
    const int rA = (wm * 64 + l16) * 64;
    const int rB = (wn * 64 + l16) * 64;

    f32x4 acc[4][4] = {};
    const int NT = K >> 6;

    auto stage = [&](int tt, int bsel) {
        bf16* as = smem + bsel * 24576;
        bf16* bs = as + 16384;
        const int koff = tt * 64;
        #pragma unroll
        for (int p = 0; p < 4; ++p)
            ldg_lds16(A + offA[p] + koff, as + p * 4096 + dstoff);
        #pragma unroll
        for (int p = 0; p < 2; ++p)
            ldg_lds16(Bt + offB[p] + koff, bs + p * 4096 + dstoff);
    };

    stage(0, 0);
    stage(1, 1);
    asm volatile("s_waitcnt vmcnt(6)" ::: "memory");
    __builtin_amdgcn_sched_barrier(0);
    __builtin_amdgcn_s_barrier();
    __builtin_amdgcn_sched_barrier(0);

    for (int t = 0; t < NT; ++t) {
        const bf16* As = smem + (t & 1) * 24576;
        const bf16* Bs = As + 16384;

        bf16x8 a0[4], b0[4];
        #pragma unroll
        for (int i = 0; i < 4; ++i)
            a0[i] = *(const bf16x8*)(As + rA + i * 1024 + c0);
        #pragma unroll
        for (int i = 0; i < 4; ++i)
            b0[i] = *(const bf16x8*)(Bs + rB + i * 1024 + c0);

        #pragma unroll
        for (int mi = 0; mi < 4; ++mi)
            #pragma unroll
            for (int ni = 0; ni < 4; ++ni)
                acc[mi][ni] = __builtin_amdgcn_mfma_f32_16x16x32_bf16(
                    a0[mi], b0[ni], acc[mi][ni], 0, 0, 0);

        bf16x8 a1[4], b1[4];
        #pragma unroll
        for (int i = 0; i < 4; ++i)
            a1[i] = *(const bf16x8*)(As + rA + i * 1024 + c1);
        #pragma unroll
        for (int i = 0; i < 4; ++i)
            b1[i] = *(const bf16x8*)(Bs + rB + i * 1024 + c1);

        asm volatile("s_waitcnt lgkmcnt(0)" ::: "memory");
        __builtin_amdgcn_sched_barrier(0);
        __builtin_amdgcn_s_barrier();
        __builtin_amdgcn_sched_barrier(0);

        if (t + 2 < NT) stage(t + 2, t & 1);

        __builtin_amdgcn_s_setprio(1);
        #pragma unroll
        for (int mi = 0; mi < 4; ++mi)
            #pragma unroll
            for (int ni = 0; ni < 4; ++ni)
                acc[mi][ni] = __builtin_amdgcn_mfma_f32_16x16x32_bf16(
                    a1[mi], b1[ni], acc[mi][ni], 0, 0, 0);
        __builtin_amdgcn_s_setprio(0);

        if (t + 2 < NT) {
            asm volatile("s_waitcnt vmcnt(6)" ::: "memory");
            __builtin_amdgcn_sched_barrier(0);
            __builtin_amdgcn_s_barrier();
            __builtin_amdgcn_sched_barrier(0);
        } else if (t == NT - 2) {
            asm volatile("s_waitcnt vmcnt(0)" ::: "memory");
            __builtin_amdgcn_sched_barrier(0);
            __builtin_amdgcn_s_barrier();
            __builtin_amdgcn_sched_barrier(0);
        }
    }

    #pragma unroll
    for (int mi = 0; mi < 4; ++mi) {
        #pragma unroll
        for (int ni = 0; ni < 4; ++ni) {
            const int row = m0 + wm * 64 + mi * 16 + quad * 4;
            const int col = n0 + wn * 64 + ni * 16 + l16;
            #pragma unroll
            for (int r = 0; r < 4; ++r)
                C[(size_t)(row + r) * 2048 + col] = acc[mi][ni][r];
        }
    }
}

// ---------------------------------------------------------------------------
// attn_v12: flash attention, sliding window 1024, causal, GQA.
// Q:[T,16,128] K:[T,4,128] Vt:[4*128][T] Y:[T,16,128] (bf16).
// ROUND-11 CHANGE vs v11: 8 waves / 512 threads / 128 q-rows per block,
// still 16 q-rows per wave (SAME per-thread registers — avoids v6's spill)
// and the SAME gload_lds dbuf + counted-vmcnt pipeline (avoids v8's
// serialized ds_writes). Grid (T/128, 16) = 512 blocks.
//  - LDS: Ks 32K + Vs 32K + Pl 8x2K = 81920 B exactly -> 2 blocks/CU
//    = 16 waves/CU (2x occupancy; the serial softmax chain now overlaps
//    with 15 other waves).
//  - One K/V tile feeds 8 waves -> staging 4 loads/thread (vmcnt 8->4),
//    K/V HBM re-reads halve.
//  - v6-proven per-wave step skip (barriers outside the skip).
// ---------------------------------------------------------------------------
__global__ __launch_bounds__(512) void attn_v12(
    const bf16* __restrict__ Q, const bf16* __restrict__ K,
    const bf16* __restrict__ Vt, bf16* __restrict__ Y,
    const float2* __restrict__ CS)
{
    const float scale = 0.08838834764831845f;  // 1/sqrt(128)

    __shared__ __align__(16) bf16 Ks[2 * 64 * 128];  // [buf][kk][128d], chunk^=(kk&15)
    __shared__ __align__(16) bf16 Vs[2 * 128 * 64];  // [buf][d][64k],   chunk^=(d&7)
    __shared__ __align__(16) bf16 Pl[8][16 * 64];    // [row][64k],      chunk^=(row&7)

    const int tid  = threadIdx.x;
    const int lane = tid & 63;
    const int wave = tid >> 6;           // 0..7
    const int quad = lane >> 4;
    const int l16  = lane & 15;

    const int i0  = (gridDim.x - 1 - blockIdx.x) * 128;  // long blocks first
    const int h   = blockIdx.y;
    const int kvh = h >> 2;
    const int q0  = i0 + wave * 16;
    bf16* Plw = Pl[wave];

    const int ks = (i0 >= 1024) ? (i0 - 1024) : 0;
    const int nsteps = (i0 + 128 - ks) >> 6;

    // staging: 4 x ldg_lds16 per thread per tile (K 16KB + V 16KB over 512
    // threads), linear LDS dest, global column chunk pre-swizzled (rule #21).
    auto stage = [&](int tt, int bsel) {
        const int k0s = ks + tt * 64;
        bf16* kd = Ks + bsel * 8192;
        bf16* vd = Vs + bsel * 8192;
        #pragma unroll
        for (int p = 0; p < 2; ++p) {
            int u = p * 512 + tid;
            int kk = u >> 4, sc = u & 15;
            ldg_lds16(K + (size_t)(k0s + kk) * 512 + kvh * 128 + (sc ^ (kk & 15)) * 8,
                      kd + u * 8);
        }
        #pragma unroll
        for (int p = 0; p < 2; ++p) {
            int u = p * 512 + tid;
            int d = u >> 3, sc = u & 7;
            ldg_lds16(Vt + (size_t)(kvh * 128 + d) * 4096 + k0s + (sc ^ (d & 7)) * 8,
                      vd + u * 8);
        }
    };

    // Q + cos/sin table loads first (oldest vmem ops); staging issues after,
    // so the RoPE math's data wait leaves the staging loads in flight.
    bf16x8 qr_[4];
    float2 csv[16];
    {
        const bf16* qp = Q + (size_t)(q0 + l16) * 2048 + h * 128 + quad * 8;
        #pragma unroll
        for (int c = 0; c < 4; ++c)
            qr_[c] = *reinterpret_cast<const bf16x8*>(qp + c * 32);
        const float2* csp = CS + (size_t)(q0 + l16) * 64 + quad * 8;
        #pragma unroll
        for (int c = 0; c < 2; ++c)
            #pragma unroll
            for (int i = 0; i < 8; ++i)
                csv[c * 8 + i] = csp[c * 32 + i];
    }

    // prologue: stage tiles 0 and 1 (tile-1 rows always < 4096 -> in-bounds;
    // max staged row = i0+127 <= 4095).
    stage(0, 0);
    stage(1, 1);

    // fused Q-RoPE via table (32 FMA, no transcendentals)
    bf16x8 qf[4];
    #pragma unroll
    for (int c = 0; c < 2; ++c) {
        #pragma unroll
        for (int i = 0; i < 8; ++i) {
            float cs_ = csv[c * 8 + i].x, sn = csv[c * 8 + i].y;
            float a = (float)qr_[c][i], b = (float)qr_[c + 2][i];
            qf[c][i]     = (bf16)(a * cs_ - b * sn);
            qf[c + 2][i] = (bf16)(b * cs_ + a * sn);
        }
    }

    f32x4 o[8] = {};
    float lsum[4] = {0.f, 0.f, 0.f, 0.f};

    asm volatile("s_waitcnt vmcnt(4)" ::: "memory");   // tile 0 landed
    __builtin_amdgcn_sched_barrier(0);
    __builtin_amdgcn_s_barrier();
    __builtin_amdgcn_sched_barrier(0);

    for (int t = 0; t < nsteps; ++t) {
        const int b  = t & 1;
        const int k0 = ks + t * 64;
        const bf16* Kb = Ks + b * 8192;
        const bf16* Vb = Vs + b * 8192;

        // per-wave step skip: this wave's 16 rows have no keys in this step
        const bool active = (k0 <= q0 + 15) && (k0 + 63 >= q0 - 1023);
        if (active) {
            // S = Q K^T, four 16-key tiles (B-frags from swizzled Ks)
            f32x4 s[4];
            __builtin_amdgcn_s_setprio(1);
            #pragma unroll
            for (int kh = 0; kh < 4; ++kh) {
                const int kk = kh * 16 + l16;
                f32x4 sv = {};
                #pragma unroll
                for (int c = 0; c < 4; ++c) {
                    bf16x8 kf = *reinterpret_cast<const bf16x8*>(
                        &Kb[kk * 128 + (((c * 4 + quad) ^ (kk & 15)) * 8)]);
                    sv = __builtin_amdgcn_mfma_f32_16x16x32_bf16(qf[c], kf, sv, 0, 0, 0);
                }
                s[kh] = sv;
            }
            __builtin_amdgcn_s_setprio(0);

            // P = exp(mask(S*scale)), fixed max 0; packed swizzled Pl write.
            const bool full = (k0 + 63 <= q0) && (q0 + 15 - k0 < 1024);
            if (full) {
                #pragma unroll
                for (int kh = 0; kh < 4; ++kh) {
                    #pragma unroll
                    for (int r = 0; r < 4; ++r) {
                        float pv = __expf(s[kh][r] * scale);
                        lsum[r] += pv;
                        const int row = quad * 4 + r;
                        const int idx = row * 64 +
                            ((((kh * 2 + (l16 >> 3)) ^ (row & 7)) << 3) | (l16 & 7));
                        Plw[idx] = (bf16)pv;
                    }
                }
            } else {
                #pragma unroll
                for (int kh = 0; kh < 4; ++kh) {
                    const int key = k0 + kh * 16 + l16;
                    #pragma unroll
                    for (int r = 0; r < 4; ++r) {
                        const int qrow = q0 + quad * 4 + r;
                        bool ok = (unsigned)(qrow - key) < 1024u;  // causal & window
                        float pv = ok ? __expf(s[kh][r] * scale) : 0.f;
                        lsum[r] += pv;
                        const int row = quad * 4 + r;
                        const int idx = row * 64 +
                            ((((kh * 2 + (l16 >> 3)) ^ (row & 7)) << 3) | (l16 & 7));
                        Plw[idx] = (bf16)pv;
                    }
                }
            }

            // PV: P (A-frags, packed swizzled Pl) x V (B-frags, swizzled Vs)
            bf16x8 pf0 = *reinterpret_cast<const bf16x8*>(
                &Plw[l16 * 64 + ((quad ^ (l16 & 7)) << 3)]);
            bf16x8 pf1 = *reinterpret_cast<const bf16x8*>(
                &Plw[l16 * 64 + (((4 + quad) ^ (l16 & 7)) << 3)]);
            __builtin_amdgcn_s_setprio(1);
            #pragma unroll
            for (int n = 0; n < 8; ++n) {
                const int d = n * 16 + l16;
                bf16x8 v0 = *reinterpret_cast<const bf16x8*>(
                    &Vb[d * 64 + (((quad) ^ (d & 7)) * 8)]);
                bf16x8 v1 = *reinterpret_cast<const bf16x8*>(
                    &Vb[d * 64 + (((4 + quad) ^ (d & 7)) * 8)]);
                o[n] = __builtin_amdgcn_mfma_f32_16x16x32_bf16(pf0, v0, o[n], 0, 0, 0);
                o[n] = __builtin_amdgcn_mfma_f32_16x16x32_bf16(pf1, v1, o[n], 0, 0, 0);
            }
            __builtin_amdgcn_s_setprio(0);
        }

        // ---- pipeline boundary: all reads of buf b done -> restage it
        asm volatile("s_waitcnt lgkmcnt(0)" ::: "memory");
        __builtin_amdgcn_sched_barrier(0);
        __builtin_amdgcn_s_barrier();
        __builtin_amdgcn_sched_barrier(0);

        if (t + 2 < nsteps) {
            stage(t + 2, b);
            asm volatile("s_waitcnt vmcnt(4)" ::: "memory");  // tile t+1 landed
        } else {
            asm volatile("s_waitcnt vmcnt(0)" ::: "memory");  // drain tail
        }
        __builtin_amdgcn_sched_barrier(0);
        __builtin_amdgcn_s_barrier();
        __builtin_amdgcn_sched_barrier(0);
    }

    // final: reduce l over the 16 lanes of each row (once), normalize, store
    #pragma unroll
    for (int r = 0; r < 4; ++r) {
        #pragma unroll
        for (int off = 1; off < 16; off <<= 1)
            lsum[r] += __shfl_xor(lsum[r], off, 64);
    }
    #pragma unroll
    for (int r = 0; r < 4; ++r) {
        int row = q0 + quad * 4 + r;
        float inv = (lsum[r] > 0.f) ? 1.f / lsum[r] : 0.f;
        #pragma unroll
        for (int n = 0; n < 8; ++n)
            Y[(size_t)row * 2048 + h * 128 + n * 16 + l16] = (bf16)(o[n][r] * inv);
    }
}

// ---------------------------------------------------------------------------
extern "C" void kernel_launch(void* const* d_in, const int* in_sizes, int n_in,
                              void* d_out, int out_size, void* d_ws, size_t ws_size,
                              hipStream_t stream)
{
    const float* x  = (const float*)d_in[0];
    const float* Wq = (const float*)d_in[1];
    const float* Wk = (const float*)d_in[2];
    const float* Wv = (const float*)d_in[3];
    const float* Wo = (const float*)d_in[4];
    float* out = (float*)d_out;

    const int T = 4096, DIM = 2048;

    // d_out (32MB fp32) hosts bf16 intermediates, all dead before final GEMM:
    //   [0,16M) Qb [T,2048] | [16M,20M) Kb [T,512] | [20M,24M) Vt [512][T]
    //   [24M,26M) CS table [4096][64] float2 (dead before gemm_out)
    char* po = (char*)d_out;
    bf16* Qb  = (bf16*)(po);
    bf16* Kb  = (bf16*)(po + (16u << 20));
    bf16* Vtb = (bf16*)(po + (20u << 20));
    float2* CS = (float2*)(po + (24u << 20));

    // ws (peak 28MB): [0,16M) xb -> later Yb ; [16M,28M) Wqkv^T -> later Wo^T
    char* ws = (char*)d_ws;
    bf16* xb    = (bf16*)(ws);
    bf16* Wqkvt = (bf16*)(ws + (16u << 20));
    bf16* Yb    = (bf16*)(ws);                 // reuses xb (dead after QKV GEMM)
    bf16* Wot   = (bf16*)(ws + (16u << 20));   // reuses Wqkv^T (dead after QKV GEMM)

    // 1. fused pre-pass: CS table + x->bf16 + vectorized W transposes
    fused_pre<<<dim3(6656), 256, 0, stream>>>(x, Wq, Wk, Wv, xb, Wqkvt, CS);

    // 2. fused QKV GEMM (256x192 tiles -> 256 blocks, full CU fill)
    gemm256_qkv<<<dim3(3072 / 192, T / 256), 512, 0, stream>>>(
        xb, Wqkvt, Qb, Kb, Vtb, DIM);

    // 3. fused mid-pass: vectorized Wo^T (freed region) + K-RoPE via CS table
    fused_mid<<<dim3(5120), 256, 0, stream>>>(Wo, Wot, CS, Kb);

    // 4. attention (v12: 8 waves / 128 q-rows per block, 16 waves/CU)
    attn_v12<<<dim3(T / 128, 16), 512, 0, stream>>>(Qb, Kb, Vtb, Yb, CS);

    // 5. output projection (256x128 deep-pipelined): -> out (fp32)
    gemm_out<<<dim3(2048 / 128, T / 256), 512, 0, stream>>>(
        Yb, Wot, out, DIM);
}